// Round 5
// baseline (242.423 us; speedup 1.0000x reference)
//
#include <hip/hip_runtime.h>
#include <hip/hip_bf16.h>

typedef unsigned int u32;
typedef unsigned short u16;

#define B_   32
#define S_   512
#define H_   256
#define NH_  8
#define HD_  32

typedef __attribute__((ext_vector_type(8))) short short8;
typedef __attribute__((ext_vector_type(4))) float f32x4;

// ---------- bf16 helpers ----------
__device__ __forceinline__ float bfl(u32 u){ union{u32 i;float f;} c; c.i = u << 16;          return c.f; }
__device__ __forceinline__ float bfh(u32 u){ union{u32 i;float f;} c; c.i = u & 0xffff0000u;  return c.f; }
__device__ __forceinline__ float bf1(u16 u){ union{u32 i;float f;} c; c.i = ((u32)u) << 16;   return c.f; }
__device__ __forceinline__ u16   f2b(float f){ __hip_bfloat16 h = __float2bfloat16(f); return *reinterpret_cast<u16*>(&h); }
__device__ __forceinline__ u32   pk2(float a, float b){ return (u32)f2b(a) | ((u32)f2b(b) << 16); }
__device__ __forceinline__ u32   bperm(int idx, u32 v){ return (u32)__builtin_amdgcn_ds_bpermute(idx, (int)v); }
__device__ __forceinline__ void  unp8(const uint4 u, float* f){
  f[0]=bfl(u.x); f[1]=bfh(u.x); f[2]=bfl(u.y); f[3]=bfh(u.y);
  f[4]=bfl(u.z); f[5]=bfh(u.z); f[6]=bfl(u.w); f[7]=bfh(u.w);
}
__device__ __forceinline__ f32x4 mfma16(short8 a, short8 b, f32x4 c){
  return __builtin_amdgcn_mfma_f32_16x16x32_bf16(a, b, c, 0, 0, 0);
}

// ---------- dtype-polymorphic loads ----------
template<int F32>
__device__ __forceinline__ void load8(const void* p, int e8, float* f) {
  if (F32) {
    const float4* q = (const float4*)p;
    const float4 a = q[e8 * 2], b = q[e8 * 2 + 1];
    f[0]=a.x; f[1]=a.y; f[2]=a.z; f[3]=a.w; f[4]=b.x; f[5]=b.y; f[6]=b.z; f[7]=b.w;
  } else {
    unp8(((const uint4*)p)[e8], f);
  }
}
template<int F32>
__device__ __forceinline__ float load1(const void* p, size_t e) {
  return F32 ? ((const float*)p)[e] : bf1(((const u16*)p)[e]);
}
template<int F32>
__device__ __forceinline__ void store1(void* p, size_t e, float v) {
  if (F32) ((float*)p)[e] = v; else ((u16*)p)[e] = f2b(v);
}
template<int F32>
__device__ __forceinline__ short8 loadBfrag(const void* wp, int row, int k0, int K) {
  if (F32) {
    const float* w = (const float*)wp + (size_t)row * K + k0;
    const float4 a = *(const float4*)w;
    const float4 b = *(const float4*)(w + 4);
    short8 r;
    r[0]=(short)f2b(a.x); r[1]=(short)f2b(a.y); r[2]=(short)f2b(a.z); r[3]=(short)f2b(a.w);
    r[4]=(short)f2b(b.x); r[5]=(short)f2b(b.y); r[6]=(short)f2b(b.z); r[7]=(short)f2b(b.w);
    return r;
  } else {
    return *(const short8*)((const u16*)wp + (size_t)row * K + k0);
  }
}

// ---------- dtype sniff (first 4KB of `inputs`) ----------
__device__ __forceinline__ int sniff_mode(const void* xin) {   // 0=bf16, 1=f32
  __shared__ int votes;
  const int tid = threadIdx.x;
  if (tid == 0) votes = 0;
  __syncthreads();
  const u32* xw = (const u32*)xin;
  int h = 0;
#pragma unroll
  for (int j = 0; j < 4; ++j) {
    const u32 u = xw[(tid << 2) + j];
    const u32 e = (u >> 7) & 0xFF;
    h += (e >= 100 && e <= 135) ? 1 : 0;
  }
  if (h) atomicAdd(&votes, h);
  __syncthreads();
  return (votes >= 512) ? 0 : 1;
}

// ============================================================
// Kernel 1: LN + QKV via MFMA. Grid 512 (M=32 rows/block), 256 thr.
// q,k: [bh][s][d] bf16. v: frag-major Vg[bh]{slot=((c*4+qd)*2+nt)*16+lr, j}
// where key=c*32+qd*8+j, dim=nt*16+lr  (attention B-frag order).
// ============================================================
template<int F32>
__global__ __launch_bounds__(256) void ln_qkv_mfma(
    const void* __restrict__ xin, const void* __restrict__ rmask,
    const void* __restrict__ wi, const void* __restrict__ gamma,
    const void* __restrict__ beta,
    u16* __restrict__ qbuf, u16* __restrict__ kbuf, u16* __restrict__ vt)
{
  if (sniff_mode(xin) != F32) return;

  __shared__ __align__(16) u16 XnF[2 * 8 * 64 * 8];   // 16 KB
  __shared__ float lmr[32];
  const int tid = threadIdx.x;
  const int l = tid & 63, w = tid >> 6;
  const int lr = l & 15, quad = l >> 4;
  const int row0 = blockIdx.x * 32;

  // ---- Phase A: LayerNorm, frag-major store ----
  {
    const int r = tid >> 5, ln = tid & 31;
    float g[8], bb[8];
    load8<F32>(gamma, ln, g);
    load8<F32>(beta,  ln, bb);
    const int c = ln >> 2, qd = ln & 3;
#pragma unroll
    for (int p = 0; p < 4; ++p) {
      const int R = p * 8 + r;
      const int grow = row0 + R;
      float x[8]; load8<F32>(xin, grow * 32 + ln, x);
      float s = 0.f, sq = 0.f;
#pragma unroll
      for (int j = 0; j < 8; ++j) { s += x[j]; sq += x[j] * x[j]; }
#pragma unroll
      for (int m = 1; m < 32; m <<= 1) { s += __shfl_xor(s, m); sq += __shfl_xor(sq, m); }
      const float mu  = s * (1.f / 256.f);
      const float var = sq * (1.f / 256.f) - mu * mu;
      const float rs  = rsqrtf(var + 1e-5f);
      short8 pk;
#pragma unroll
      for (int j = 0; j < 8; ++j) pk[j] = (short)f2b((x[j] - mu) * rs * g[j] + bb[j]);
      const int t = R >> 4, rm = R & 15;
      *(short8*)(XnF + (((t * 8 + c) * 64 + qd * 16 + rm) << 3)) = pk;
      if (ln == 0) lmr[R] = logf(load1<F32>(rmask, grow));
    }
  }
  __syncthreads();

  // ---- Phase B: GEMM ----
  const int bb_ = row0 >> 9;
  const int sB  = (row0 & 511);
  for (int nt = 0; nt < 12; ++nt) {
    const int nAbs = (w * 12 + nt) * 16;
    short8 Bf[8];
#pragma unroll
    for (int c = 0; c < 8; ++c) Bf[c] = loadBfrag<F32>(wi, nAbs + lr, c * 32 + quad * 8, 256);

    f32x4 a0 = {0.f,0.f,0.f,0.f}, a1 = {0.f,0.f,0.f,0.f};
#pragma unroll
    for (int c = 0; c < 8; ++c) {
      const short8 f0 = *(const short8*)(XnF + ((c       * 64 + l) << 3));
      const short8 f1 = *(const short8*)(XnF + (((8 + c) * 64 + l) << 3));
      a0 = mfma16(f0, Bf[c], a0);
      a1 = mfma16(f1, Bf[c], a1);
    }

    const int type = nAbs >> 8;              // 0=q 1=k 2=v
    const int d    = (nAbs & 255) + lr;
    const int h    = d >> 5, dd = d & 31;
    const int bh   = bb_ * NH_ + h;
#pragma unroll
    for (int m = 0; m < 2; ++m) {
      const f32x4 acc = m ? a1 : a0;
      const int sLoc = m * 16 + quad * 4;
      if (type == 0) {
#pragma unroll
        for (int i = 0; i < 4; ++i) {
          float qv = acc[i]; qv = qv * qv + 1e-6f;
          qbuf[((size_t)bh * S_ + (sB + sLoc + i)) * HD_ + dd] = f2b(qv);
        }
      } else if (type == 1) {
#pragma unroll
        for (int i = 0; i < 4; ++i)
          kbuf[((size_t)bh * S_ + (sB + sLoc + i)) * HD_ + dd] = f2b(acc[i] + lmr[sLoc + i]);
      } else {
        // frag-major V: key = sB + sLoc + i -> c=sB>>5, qd=2m+(quad>>1), j=(quad&1)*4+i
        const int ntv = dd >> 4, lrv = dd & 15;
        const int slot = (((sB >> 5) * 4 + 2 * m + (quad >> 1)) * 2 + ntv) * 16 + lrv;
        uint2 pkv;
        pkv.x = pk2(acc[0], acc[1]);
        pkv.y = pk2(acc[2], acc[3]);
        *(uint2*)(vt + (size_t)bh * (S_ * HD_) + slot * 8 + (quad & 1) * 4) = pkv;
      }
    }
  }
}

// ============================================================
// Kernel 2: MFMA flash attention. Grid 512 = (bh, s-half), 256 thr.
// K + V both staged in LDS frag-major (64 KB exactly).
// P transform C->A layout via ds_bpermute (no LDS buffer).
// ============================================================
__global__ __launch_bounds__(256, 2) void attn_mfma(
    const u16* __restrict__ qbuf, const u16* __restrict__ kbuf,
    const u16* __restrict__ vt, u16* __restrict__ ctx)
{
  __shared__ __align__(16) u16 Kf[16384];   // 32 KB: slot = kt*64 + l  (A-frag order)
  __shared__ __align__(16) u16 Vf[16384];   // 32 KB: slot = (c*8+2*quad+nt)*16+lr (B-frag order)
  const int tid = threadIdx.x;
  const int bh = blockIdx.x >> 1, sh = blockIdx.x & 1;
  const int l = tid & 63, w = tid >> 6;
  const int lr = l & 15, quad = l >> 4;
  const size_t kvbase = (size_t)bh * (S_ * HD_);

  // ---- stage K (shuffle to frag-major) and V (straight copy) ----
  {
    const uint4* ks = (const uint4*)(kbuf + kvbase);
    const uint4* vs = (const uint4*)(vt + kvbase);
    uint4* kd = (uint4*)Kf;
    uint4* vd = (uint4*)Vf;
#pragma unroll
    for (int it = 0; it < 8; ++it) {
      const int e8 = it * 256 + tid;
      const int key = e8 >> 2, dq = e8 & 3;
      kd[((key >> 4) * 4 + dq) * 16 + (key & 15)] = ks[e8];
      vd[e8] = vs[e8];
    }
  }
  __syncthreads();

  const float cE = 0.17677669529663688f * 1.4426950408889634f; // (1/sqrt(32))*log2(e)
  const int b = bh >> 3, h = bh & 7;
  const int sl0 = (((quad & 1) * 2) * 16 + lr) * 4;   // bpermute byte idx, quad_s base
  const int sl1 = sl0 + 64;                            // +16 lanes
  const bool hiQuad = (quad >= 2);

  for (int qt = 0; qt < 4; ++qt) {
    const int q0 = sh * 256 + w * 64 + qt * 16;
    const short8 qf = *(const short8*)(qbuf + kvbase + (size_t)(q0 + lr) * HD_ + quad * 8);

    // ---- QK^T: acc[kt] row=key(quad*4+r), col=query(lr) ----
    f32x4 acc[32];
#pragma unroll
    for (int kt = 0; kt < 32; ++kt) {
      const short8 kf = *(const short8*)(Kf + ((kt * 64 + l) << 3));
      f32x4 z = {0.f, 0.f, 0.f, 0.f};
      acc[kt] = mfma16(kf, qf, z);
    }

    // ---- softmax over keys for query col=lr ----
    float mx = -1e30f;
#pragma unroll
    for (int kt = 0; kt < 32; ++kt) {
#pragma unroll
      for (int r = 0; r < 4; ++r) mx = fmaxf(mx, acc[kt][r]);
    }
    mx = fmaxf(mx, __shfl_xor(mx, 16));
    mx = fmaxf(mx, __shfl_xor(mx, 32));
    const float mE = mx * cE;
    float sum = 0.f;
#pragma unroll
    for (int kt = 0; kt < 32; ++kt) {
#pragma unroll
      for (int r = 0; r < 4; ++r) {
        const float p = exp2f(fmaf(acc[kt][r], cE, -mE));
        acc[kt][r] = p; sum += p;
      }
    }
    sum += __shfl_xor(sum, 16);
    sum += __shfl_xor(sum, 32);
    const float inv = 1.f / sum;

    // ---- PV: P C->A layout via bpermute; V from LDS (B-frag order) ----
    f32x4 o0 = {0.f,0.f,0.f,0.f}, o1 = {0.f,0.f,0.f,0.f};
#pragma unroll
    for (int c = 0; c < 16; ++c) {
      // source packs: P32[t][i] = keys (2c+t)*16 + quad*4 + 2i,2i+1 ; query lr
      const u32 p00 = pk2(acc[2*c][0],   acc[2*c][1]);
      const u32 p01 = pk2(acc[2*c][2],   acc[2*c][3]);
      const u32 p10 = pk2(acc[2*c+1][0], acc[2*c+1][1]);
      const u32 p11 = pk2(acc[2*c+1][2], acc[2*c+1][3]);
      union { u32 u[4]; short8 s; } pa;
      {
        const u32 a0lo = bperm(sl0, p00), a0hi = bperm(sl0, p10);
        const u32 a1lo = bperm(sl0, p01), a1hi = bperm(sl0, p11);
        const u32 a2lo = bperm(sl1, p00), a2hi = bperm(sl1, p10);
        const u32 a3lo = bperm(sl1, p01), a3hi = bperm(sl1, p11);
        pa.u[0] = hiQuad ? a0hi : a0lo;
        pa.u[1] = hiQuad ? a1hi : a1lo;
        pa.u[2] = hiQuad ? a2hi : a2lo;
        pa.u[3] = hiQuad ? a3hi : a3lo;
      }
      const short8 v0 = *(const short8*)(Vf + (((c * 8 + 2 * quad) * 16 + lr) << 3));
      const short8 v1 = *(const short8*)(Vf + ((((c * 8 + 2 * quad) * 16 + lr) << 3) + 128));
      o0 = mfma16(pa.s, v0, o0);
      o1 = mfma16(pa.s, v1, o1);
    }

    // ---- epilogue ----
#pragma unroll
    for (int r = 0; r < 4; ++r) {
      const int qq = quad * 4 + r;
      const float iv = __shfl(inv, (l & 48) | qq);
      u16* dst = ctx + ((size_t)(b * S_ + q0 + qq)) * H_ + h * HD_;
      dst[lr]      = f2b(o0[r] * iv);
      dst[16 + lr] = f2b(o1[r] * iv);
    }
  }
}

// ============================================================
// Kernel 3: out-proj via MFMA + residual + sqrt(1/2).
// ============================================================
template<int F32>
__global__ __launch_bounds__(256) void proj_mfma(
    const u16* __restrict__ ctx, const void* __restrict__ xin,
    const void* __restrict__ wo, void* __restrict__ out)
{
  if (sniff_mode(xin) != F32) return;

  __shared__ __align__(16) u16 XnF[2 * 8 * 64 * 8];   // 16 KB
  const int tid = threadIdx.x;
  const int l = tid & 63, w = tid >> 6;
  const int lr = l & 15, quad = l >> 4;
  const int row0 = blockIdx.x * 32;

#pragma unroll
  for (int it = 0; it < 4; ++it) {
    const int idx = it * 256 + tid;
    const int R = idx >> 5, u4 = idx & 31;
    const uint4 cv = ((const uint4*)ctx)[(size_t)row0 * 32 + idx];
    const int t = R >> 4, c = u4 >> 2, qd = u4 & 3, rm = R & 15;
    *(uint4*)(XnF + (((t * 8 + c) * 64 + qd * 16 + rm) << 3)) = cv;
  }
  __syncthreads();

  for (int nt = 0; nt < 4; ++nt) {
    const int n0 = (w * 4 + nt) * 16;
    short8 Bf[8];
#pragma unroll
    for (int c = 0; c < 8; ++c) Bf[c] = loadBfrag<F32>(wo, n0 + lr, c * 32 + quad * 8, 256);

    f32x4 a0 = {0.f,0.f,0.f,0.f}, a1 = {0.f,0.f,0.f,0.f};
#pragma unroll
    for (int c = 0; c < 8; ++c) {
      const short8 f0 = *(const short8*)(XnF + ((c       * 64 + l) << 3));
      const short8 f1 = *(const short8*)(XnF + (((8 + c) * 64 + l) << 3));
      a0 = mfma16(f0, Bf[c], a0);
      a1 = mfma16(f1, Bf[c], a1);
    }

#pragma unroll
    for (int m = 0; m < 2; ++m) {
      const f32x4 acc = m ? a1 : a0;
#pragma unroll
      for (int i = 0; i < 4; ++i) {
        const size_t e = (size_t)(row0 + m * 16 + quad * 4 + i) * H_ + n0 + lr;
        const float xi = load1<F32>(xin, e);
        store1<F32>(out, e, (acc[i] + xi) * 0.70710678f);
      }
    }
  }
}

// ============================================================
extern "C" void kernel_launch(void* const* d_in, const int* in_sizes, int n_in,
                              void* d_out, int out_size, void* d_ws, size_t ws_size,
                              hipStream_t stream)
{
  const void* xin   = d_in[0];
  const void* rmask = d_in[1];
  const void* wi    = d_in[2];
  const void* wo    = d_in[3];
  const void* gam   = d_in[4];
  const void* bet   = d_in[5];

  u16* q   = (u16*)d_ws;                   // [256][512][32] bf16 (8 MB)
  u16* k   = q + 4194304;
  u16* vt  = k + 4194304;                  // frag-major V (8 MB)
  u16* cxb = vt + 4194304;                 // ctx [32,512,256] bf16 (8 MB)

  ln_qkv_mfma<0><<<512, 256, 0, stream>>>(xin, rmask, wi, gam, bet, q, k, vt);
  ln_qkv_mfma<1><<<512, 256, 0, stream>>>(xin, rmask, wi, gam, bet, q, k, vt);
  attn_mfma     <<<512, 256, 0, stream>>>(q, k, vt, cxb);
  proj_mfma<0>  <<<512, 256, 0, stream>>>(cxb, xin, wo, d_out);
  proj_mfma<1>  <<<512, 256, 0, stream>>>(cxb, xin, wo, d_out);
}

// Round 6
// 228.805 us; speedup vs baseline: 1.0595x; 1.0595x over previous
//
#include <hip/hip_runtime.h>
#include <hip/hip_bf16.h>

typedef unsigned int u32;
typedef unsigned short u16;

#define B_   32
#define S_   512
#define H_   256
#define NH_  8
#define HD_  32

typedef __attribute__((ext_vector_type(8))) short short8;
typedef __attribute__((ext_vector_type(4))) float f32x4;

// ---------- bf16 helpers ----------
__device__ __forceinline__ float bfl(u32 u){ union{u32 i;float f;} c; c.i = u << 16;          return c.f; }
__device__ __forceinline__ float bfh(u32 u){ union{u32 i;float f;} c; c.i = u & 0xffff0000u;  return c.f; }
__device__ __forceinline__ float bf1(u16 u){ union{u32 i;float f;} c; c.i = ((u32)u) << 16;   return c.f; }
__device__ __forceinline__ u16   f2b(float f){ __hip_bfloat16 h = __float2bfloat16(f); return *reinterpret_cast<u16*>(&h); }
__device__ __forceinline__ u32   pk2(float a, float b){ return (u32)f2b(a) | ((u32)f2b(b) << 16); }
__device__ __forceinline__ u32   bperm(int idx, u32 v){ return (u32)__builtin_amdgcn_ds_bpermute(idx, (int)v); }
__device__ __forceinline__ void  unp8(const uint4 u, float* f){
  f[0]=bfl(u.x); f[1]=bfh(u.x); f[2]=bfl(u.y); f[3]=bfh(u.y);
  f[4]=bfl(u.z); f[5]=bfh(u.z); f[6]=bfl(u.w); f[7]=bfh(u.w);
}
__device__ __forceinline__ f32x4 mfma16(short8 a, short8 b, f32x4 c){
  return __builtin_amdgcn_mfma_f32_16x16x32_bf16(a, b, c, 0, 0, 0);
}

// ---------- dtype-polymorphic loads/stores ----------
template<int F32>
__device__ __forceinline__ void load8(const void* p, int e8, float* f) {
  if (F32) {
    const float4* q = (const float4*)p;
    const float4 a = q[e8 * 2], b = q[e8 * 2 + 1];
    f[0]=a.x; f[1]=a.y; f[2]=a.z; f[3]=a.w; f[4]=b.x; f[5]=b.y; f[6]=b.z; f[7]=b.w;
  } else {
    unp8(((const uint4*)p)[e8], f);
  }
}
template<int F32>
__device__ __forceinline__ void store8(void* p, int e8, const float* f) {
  if (F32) {
    float4* q = (float4*)p;
    q[e8 * 2]     = make_float4(f[0], f[1], f[2], f[3]);
    q[e8 * 2 + 1] = make_float4(f[4], f[5], f[6], f[7]);
  } else {
    uint4 u;
    u.x = pk2(f[0], f[1]); u.y = pk2(f[2], f[3]);
    u.z = pk2(f[4], f[5]); u.w = pk2(f[6], f[7]);
    ((uint4*)p)[e8] = u;
  }
}
template<int F32>
__device__ __forceinline__ float load1(const void* p, size_t e) {
  return F32 ? ((const float*)p)[e] : bf1(((const u16*)p)[e]);
}
template<int F32>
__device__ __forceinline__ short8 loadBfrag(const void* wp, int row, int k0, int K) {
  if (F32) {
    const float* w = (const float*)wp + (size_t)row * K + k0;
    const float4 a = *(const float4*)w;
    const float4 b = *(const float4*)(w + 4);
    short8 r;
    r[0]=(short)f2b(a.x); r[1]=(short)f2b(a.y); r[2]=(short)f2b(a.z); r[3]=(short)f2b(a.w);
    r[4]=(short)f2b(b.x); r[5]=(short)f2b(b.y); r[6]=(short)f2b(b.z); r[7]=(short)f2b(b.w);
    return r;
  } else {
    return *(const short8*)((const u16*)wp + (size_t)row * K + k0);
  }
}

// ---------- dtype sniff (first 4KB of `inputs`) ----------
__device__ __forceinline__ int sniff_mode(const void* xin) {   // 0=bf16, 1=f32
  __shared__ int votes;
  const int tid = threadIdx.x;
  if (tid == 0) votes = 0;
  __syncthreads();
  const u32* xw = (const u32*)xin;
  int h = 0;
#pragma unroll
  for (int j = 0; j < 4; ++j) {
    const u32 u = xw[(tid << 2) + j];
    const u32 e = (u >> 7) & 0xFF;
    h += (e >= 100 && e <= 135) ? 1 : 0;
  }
  if (h) atomicAdd(&votes, h);
  __syncthreads();
  return (votes >= 512) ? 0 : 1;
}

// ============================================================
// Kernel 1: LN + QKV via MFMA (unchanged from R5).
// q,k: [bh][s][d] bf16. v: frag-major attention B-frag order.
// ============================================================
template<int F32>
__global__ __launch_bounds__(256) void ln_qkv_mfma(
    const void* __restrict__ xin, const void* __restrict__ rmask,
    const void* __restrict__ wi, const void* __restrict__ gamma,
    const void* __restrict__ beta,
    u16* __restrict__ qbuf, u16* __restrict__ kbuf, u16* __restrict__ vt)
{
  if (sniff_mode(xin) != F32) return;

  __shared__ __align__(16) u16 XnF[2 * 8 * 64 * 8];   // 16 KB
  __shared__ float lmr[32];
  const int tid = threadIdx.x;
  const int l = tid & 63, w = tid >> 6;
  const int lr = l & 15, quad = l >> 4;
  const int row0 = blockIdx.x * 32;

  // ---- Phase A: LayerNorm, frag-major store ----
  {
    const int r = tid >> 5, ln = tid & 31;
    float g[8], bb[8];
    load8<F32>(gamma, ln, g);
    load8<F32>(beta,  ln, bb);
    const int c = ln >> 2, qd = ln & 3;
#pragma unroll
    for (int p = 0; p < 4; ++p) {
      const int R = p * 8 + r;
      const int grow = row0 + R;
      float x[8]; load8<F32>(xin, grow * 32 + ln, x);
      float s = 0.f, sq = 0.f;
#pragma unroll
      for (int j = 0; j < 8; ++j) { s += x[j]; sq += x[j] * x[j]; }
#pragma unroll
      for (int m = 1; m < 32; m <<= 1) { s += __shfl_xor(s, m); sq += __shfl_xor(sq, m); }
      const float mu  = s * (1.f / 256.f);
      const float var = sq * (1.f / 256.f) - mu * mu;
      const float rs  = rsqrtf(var + 1e-5f);
      short8 pk;
#pragma unroll
      for (int j = 0; j < 8; ++j) pk[j] = (short)f2b((x[j] - mu) * rs * g[j] + bb[j]);
      const int t = R >> 4, rm = R & 15;
      *(short8*)(XnF + (((t * 8 + c) * 64 + qd * 16 + rm) << 3)) = pk;
      if (ln == 0) lmr[R] = logf(load1<F32>(rmask, grow));
    }
  }
  __syncthreads();

  // ---- Phase B: GEMM ----
  const int bb_ = row0 >> 9;
  const int sB  = (row0 & 511);
  for (int nt = 0; nt < 12; ++nt) {
    const int nAbs = (w * 12 + nt) * 16;
    short8 Bf[8];
#pragma unroll
    for (int c = 0; c < 8; ++c) Bf[c] = loadBfrag<F32>(wi, nAbs + lr, c * 32 + quad * 8, 256);

    f32x4 a0 = {0.f,0.f,0.f,0.f}, a1 = {0.f,0.f,0.f,0.f};
#pragma unroll
    for (int c = 0; c < 8; ++c) {
      const short8 f0 = *(const short8*)(XnF + ((c       * 64 + l) << 3));
      const short8 f1 = *(const short8*)(XnF + (((8 + c) * 64 + l) << 3));
      a0 = mfma16(f0, Bf[c], a0);
      a1 = mfma16(f1, Bf[c], a1);
    }

    const int type = nAbs >> 8;              // 0=q 1=k 2=v
    const int d    = (nAbs & 255) + lr;
    const int h    = d >> 5, dd = d & 31;
    const int bh   = bb_ * NH_ + h;
#pragma unroll
    for (int m = 0; m < 2; ++m) {
      const f32x4 acc = m ? a1 : a0;
      const int sLoc = m * 16 + quad * 4;
      if (type == 0) {
#pragma unroll
        for (int i = 0; i < 4; ++i) {
          float qv = acc[i]; qv = qv * qv + 1e-6f;
          qbuf[((size_t)bh * S_ + (sB + sLoc + i)) * HD_ + dd] = f2b(qv);
        }
      } else if (type == 1) {
#pragma unroll
        for (int i = 0; i < 4; ++i)
          kbuf[((size_t)bh * S_ + (sB + sLoc + i)) * HD_ + dd] = f2b(acc[i] + lmr[sLoc + i]);
      } else {
        const int ntv = dd >> 4, lrv = dd & 15;
        const int slot = (((sB >> 5) * 4 + 2 * m + (quad >> 1)) * 2 + ntv) * 16 + lrv;
        uint2 pkv;
        pkv.x = pk2(acc[0], acc[1]);
        pkv.y = pk2(acc[2], acc[3]);
        *(uint2*)(vt + (size_t)bh * (S_ * HD_) + slot * 8 + (quad & 1) * 4) = pkv;
      }
    }
  }
}

// ============================================================
// Kernel 2: LDS-free MFMA flash attention.
// Grid 2048 = (sq 0..7)*256 + bh. bh = blockIdx&255 (XCD swizzle:
// all 8 s-chunks of one bh land on one XCD -> K/V fetched once/XCD).
// 4 waves x 16 queries. K,V read direct from global (coalesced frag
// order, L1/L2-resident). No __syncthreads. ctx layout: [bh][s][hd].
// ============================================================
__global__ __launch_bounds__(256) void attn_mfma(
    const u16* __restrict__ qbuf, const u16* __restrict__ kbuf,
    const u16* __restrict__ vt, u16* __restrict__ ctx)
{
  __shared__ __align__(16) u16 OB[4][16 * 40];   // wave-private out transpose (5 KB)
  const int tid = threadIdx.x;
  const int bh = blockIdx.x & 255, sq = blockIdx.x >> 8;
  const int l = tid & 63, w = tid >> 6;
  const int lr = l & 15, quad = l >> 4;
  const size_t kvbase = (size_t)bh * (S_ * HD_);
  const int q0 = sq * 64 + w * 16;

  const float cE = 0.17677669529663688f * 1.4426950408889634f; // (1/sqrt(32))*log2(e)
  const int sl0 = (((quad & 1) * 2) * 16 + lr) * 4;   // bpermute byte idx
  const int sl1 = sl0 + 64;
  const bool hiQuad = (quad >= 2);

  // B-frag: Q[q0+lr][quad*8..+7]
  const short8 qf = *(const short8*)(qbuf + kvbase + (size_t)(q0 + lr) * HD_ + quad * 8);

  // ---- QK^T: acc[kt] row=key(quad*4+r), col=query(lr). K direct from global (A-frag order) ----
  const u16* kp = kbuf + kvbase + (size_t)lr * HD_ + quad * 8;
  f32x4 acc[32];
#pragma unroll
  for (int kt = 0; kt < 32; ++kt) {
    const short8 kf = *(const short8*)(kp + kt * (16 * HD_));
    f32x4 z = {0.f, 0.f, 0.f, 0.f};
    acc[kt] = mfma16(kf, qf, z);
  }

  // ---- softmax over keys for query col=lr ----
  float mx = -1e30f;
#pragma unroll
  for (int kt = 0; kt < 32; ++kt) {
#pragma unroll
    for (int r = 0; r < 4; ++r) mx = fmaxf(mx, acc[kt][r]);
  }
  mx = fmaxf(mx, __shfl_xor(mx, 16));
  mx = fmaxf(mx, __shfl_xor(mx, 32));
  const float mE = mx * cE;
  float sum = 0.f;
#pragma unroll
  for (int kt = 0; kt < 32; ++kt) {
#pragma unroll
    for (int r = 0; r < 4; ++r) {
      const float p = exp2f(fmaf(acc[kt][r], cE, -mE));
      acc[kt][r] = p; sum += p;
    }
  }
  sum += __shfl_xor(sum, 16);
  sum += __shfl_xor(sum, 32);
  const float inv = 1.f / sum;

  // ---- PV: P C->A layout via bpermute; V direct from global (B-frag order) ----
  const u16* vp = vt + kvbase;
  f32x4 o0 = {0.f,0.f,0.f,0.f}, o1 = {0.f,0.f,0.f,0.f};
#pragma unroll
  for (int c = 0; c < 16; ++c) {
    const u32 p00 = pk2(acc[2*c][0],   acc[2*c][1]);
    const u32 p01 = pk2(acc[2*c][2],   acc[2*c][3]);
    const u32 p10 = pk2(acc[2*c+1][0], acc[2*c+1][1]);
    const u32 p11 = pk2(acc[2*c+1][2], acc[2*c+1][3]);
    union { u32 u[4]; short8 s; } pa;
    {
      const u32 a0lo = bperm(sl0, p00), a0hi = bperm(sl0, p10);
      const u32 a1lo = bperm(sl0, p01), a1hi = bperm(sl0, p11);
      const u32 a2lo = bperm(sl1, p00), a2hi = bperm(sl1, p10);
      const u32 a3lo = bperm(sl1, p01), a3hi = bperm(sl1, p11);
      pa.u[0] = hiQuad ? a0hi : a0lo;
      pa.u[1] = hiQuad ? a1hi : a1lo;
      pa.u[2] = hiQuad ? a2hi : a2lo;
      pa.u[3] = hiQuad ? a3hi : a3lo;
    }
    const short8 v0 = *(const short8*)(vp + (((c * 8 + 2 * quad) * 16 + lr) << 3));
    const short8 v1 = *(const short8*)(vp + ((((c * 8 + 2 * quad) * 16 + lr) << 3) + 128));
    o0 = mfma16(pa.s, v0, o0);
    o1 = mfma16(pa.s, v1, o1);
  }

  // ---- epilogue: scale, wave-private LDS transpose, coalesced 16B store ----
  u16* ob = OB[w];
#pragma unroll
  for (int r = 0; r < 4; ++r) {
    const int qq = quad * 4 + r;
    const float iv = __shfl(inv, (l & 48) | qq);
    ob[qq * 40 + lr]      = f2b(o0[r] * iv);
    ob[qq * 40 + 16 + lr] = f2b(o1[r] * iv);
  }
  const uint4 ov = *(const uint4*)(ob + (l >> 2) * 40 + (l & 3) * 8);
  *(uint4*)(ctx + kvbase + (size_t)(q0 + (l >> 2)) * HD_ + (l & 3) * 8) = ov;
}

// ============================================================
// Kernel 3: out-proj via MFMA + residual + sqrt(1/2).
// ctx layout [bh][s][hd]. Coalesced out stores via LDS result tile.
// ============================================================
template<int F32>
__global__ __launch_bounds__(256) void proj_mfma(
    const u16* __restrict__ ctx, const void* __restrict__ xin,
    const void* __restrict__ wo, void* __restrict__ out)
{
  if (sniff_mode(xin) != F32) return;

  __shared__ __align__(16) u16 XnF[2 * 8 * 64 * 8];   // 16 KB
  __shared__ __align__(16) u16 OutB[32 * 264];        // 16.5 KB (264 pad: bank rotate 4/row)
  const int tid = threadIdx.x;
  const int l = tid & 63, w = tid >> 6;
  const int lr = l & 15, quad = l >> 4;
  const int row0 = blockIdx.x * 32;
  const int b = row0 >> 9, s0 = row0 & 511;

  // ---- stage ctx -> A-frag LDS (swizzled: qd' = qd ^ (rm&3), conflict-free) ----
#pragma unroll
  for (int it = 0; it < 4; ++it) {
    const int idx = it * 256 + tid;
    const int dq = idx & 3, sl = (idx >> 2) & 31, h = idx >> 7;
    const uint4 cv = *(const uint4*)(ctx + ((size_t)(b * 8 + h) * S_ + s0 + sl) * HD_ + dq * 8);
    const int t = sl >> 4, rm = sl & 15;
    const int qds = dq ^ (rm & 3);
    *(uint4*)(XnF + (((t * 8 + h) * 64 + qds * 16 + rm) << 3)) = cv;
  }
  __syncthreads();

  const int lsw = (quad ^ (lr & 3)) * 16 + lr;   // swizzled A-frag read slot
  for (int nt = 0; nt < 4; ++nt) {
    const int n0 = (w * 4 + nt) * 16;
    short8 Bf[8];
#pragma unroll
    for (int c = 0; c < 8; ++c) Bf[c] = loadBfrag<F32>(wo, n0 + lr, c * 32 + quad * 8, 256);

    f32x4 a0 = {0.f,0.f,0.f,0.f}, a1 = {0.f,0.f,0.f,0.f};
#pragma unroll
    for (int c = 0; c < 8; ++c) {
      const short8 f0 = *(const short8*)(XnF + ((c       * 64 + lsw) << 3));
      const short8 f1 = *(const short8*)(XnF + (((8 + c) * 64 + lsw) << 3));
      a0 = mfma16(f0, Bf[c], a0);
      a1 = mfma16(f1, Bf[c], a1);
    }

#pragma unroll
    for (int m = 0; m < 2; ++m) {
      const f32x4 acc = m ? a1 : a0;
#pragma unroll
      for (int i = 0; i < 4; ++i)
        OutB[(m * 16 + quad * 4 + i) * 264 + n0 + lr] = f2b(acc[i]);
    }
  }
  __syncthreads();

  // ---- epilogue: residual + scale, vectorized coalesced store ----
  const int r  = tid >> 3;             // 0..31
  const int c8 = (tid & 7) * 4;        // uint4 index base within row (x8 elems)
#pragma unroll
  for (int j8 = 0; j8 < 4; ++j8) {
    float xv[8]; load8<F32>(xin, (row0 + r) * 32 + c8 + j8, xv);
    float pv[8]; unp8(*(const uint4*)(OutB + r * 264 + (c8 + j8) * 8), pv);
    float ov[8];
#pragma unroll
    for (int j = 0; j < 8; ++j) ov[j] = (pv[j] + xv[j]) * 0.70710678f;
    store8<F32>(out, (row0 + r) * 32 + c8 + j8, ov);
  }
}

// ============================================================
extern "C" void kernel_launch(void* const* d_in, const int* in_sizes, int n_in,
                              void* d_out, int out_size, void* d_ws, size_t ws_size,
                              hipStream_t stream)
{
  const void* xin   = d_in[0];
  const void* rmask = d_in[1];
  const void* wi    = d_in[2];
  const void* wo    = d_in[3];
  const void* gam   = d_in[4];
  const void* bet   = d_in[5];

  u16* q   = (u16*)d_ws;                   // [256][512][32] bf16 (8 MB)
  u16* k   = q + 4194304;
  u16* vt  = k + 4194304;                  // frag-major V (8 MB)
  u16* cxb = vt + 4194304;                 // ctx [bh][s][hd] bf16 (8 MB)

  ln_qkv_mfma<0><<<512,  256, 0, stream>>>(xin, rmask, wi, gam, bet, q, k, vt);
  ln_qkv_mfma<1><<<512,  256, 0, stream>>>(xin, rmask, wi, gam, bet, q, k, vt);
  attn_mfma     <<<2048, 256, 0, stream>>>(q, k, vt, cxb);
  proj_mfma<0>  <<<512,  256, 0, stream>>>(cxb, xin, wo, d_out);
  proj_mfma<1>  <<<512,  256, 0, stream>>>(cxb, xin, wo, d_out);
}

// Round 7
// 213.736 us; speedup vs baseline: 1.1342x; 1.0705x over previous
//
#include <hip/hip_runtime.h>
#include <hip/hip_bf16.h>

typedef unsigned int u32;
typedef unsigned short u16;

#define B_   32
#define S_   512
#define H_   256
#define NH_  8
#define HD_  32

typedef __attribute__((ext_vector_type(8))) short short8;
typedef __attribute__((ext_vector_type(4))) float f32x4;

// ---------- bf16 helpers ----------
__device__ __forceinline__ float bfl(u32 u){ union{u32 i;float f;} c; c.i = u << 16;          return c.f; }
__device__ __forceinline__ float bfh(u32 u){ union{u32 i;float f;} c; c.i = u & 0xffff0000u;  return c.f; }
__device__ __forceinline__ float bf1(u16 u){ union{u32 i;float f;} c; c.i = ((u32)u) << 16;   return c.f; }
__device__ __forceinline__ u16   f2b(float f){ __hip_bfloat16 h = __float2bfloat16(f); return *reinterpret_cast<u16*>(&h); }
__device__ __forceinline__ u32   pk2(float a, float b){ return (u32)f2b(a) | ((u32)f2b(b) << 16); }
__device__ __forceinline__ void  unp8(const uint4 u, float* f){
  f[0]=bfl(u.x); f[1]=bfh(u.x); f[2]=bfl(u.y); f[3]=bfh(u.y);
  f[4]=bfl(u.z); f[5]=bfh(u.z); f[6]=bfl(u.w); f[7]=bfh(u.w);
}
__device__ __forceinline__ f32x4 mfma16(short8 a, short8 b, f32x4 c){
  return __builtin_amdgcn_mfma_f32_16x16x32_bf16(a, b, c, 0, 0, 0);
}

// ---------- dtype-polymorphic loads/stores ----------
template<int F32>
__device__ __forceinline__ void load8(const void* p, int e8, float* f) {
  if (F32) {
    const float4* q = (const float4*)p;
    const float4 a = q[e8 * 2], b = q[e8 * 2 + 1];
    f[0]=a.x; f[1]=a.y; f[2]=a.z; f[3]=a.w; f[4]=b.x; f[5]=b.y; f[6]=b.z; f[7]=b.w;
  } else {
    unp8(((const uint4*)p)[e8], f);
  }
}
template<int F32>
__device__ __forceinline__ void store8(void* p, int e8, const float* f) {
  if (F32) {
    float4* q = (float4*)p;
    q[e8 * 2]     = make_float4(f[0], f[1], f[2], f[3]);
    q[e8 * 2 + 1] = make_float4(f[4], f[5], f[6], f[7]);
  } else {
    uint4 u;
    u.x = pk2(f[0], f[1]); u.y = pk2(f[2], f[3]);
    u.z = pk2(f[4], f[5]); u.w = pk2(f[6], f[7]);
    ((uint4*)p)[e8] = u;
  }
}
template<int F32>
__device__ __forceinline__ float load1(const void* p, size_t e) {
  return F32 ? ((const float*)p)[e] : bf1(((const u16*)p)[e]);
}
template<int F32>
__device__ __forceinline__ short8 loadBfrag(const void* wp, int row, int k0, int K) {
  if (F32) {
    const float* w = (const float*)wp + (size_t)row * K + k0;
    const float4 a = *(const float4*)w;
    const float4 b = *(const float4*)(w + 4);
    short8 r;
    r[0]=(short)f2b(a.x); r[1]=(short)f2b(a.y); r[2]=(short)f2b(a.z); r[3]=(short)f2b(a.w);
    r[4]=(short)f2b(b.x); r[5]=(short)f2b(b.y); r[6]=(short)f2b(b.z); r[7]=(short)f2b(b.w);
    return r;
  } else {
    return *(const short8*)((const u16*)wp + (size_t)row * K + k0);
  }
}

// ---------- dtype sniff (first 4KB of `inputs`) ----------
__device__ __forceinline__ int sniff_mode(const void* xin) {   // 0=bf16, 1=f32
  __shared__ int votes;
  const int tid = threadIdx.x;
  if (tid == 0) votes = 0;
  __syncthreads();
  const u32* xw = (const u32*)xin;
  int h = 0;
#pragma unroll
  for (int j = 0; j < 4; ++j) {
    const u32 u = xw[(tid << 2) + j];
    const u32 e = (u >> 7) & 0xFF;
    h += (e >= 100 && e <= 135) ? 1 : 0;
  }
  if (h) atomicAdd(&votes, h);
  __syncthreads();
  return (votes >= 512) ? 0 : 1;
}

// ============================================================
// Kernel 1: LN + QKV via MFMA. Grid 1024 = (m-block 0..511) x (nhalf).
// Each wave: 6 n-tiles, double-buffered B-frag prefetch.
// q,k: [bh][s][d] bf16. v: sigma-permuted attn B-frag order:
//   slot16(c,half,quad,dimlr) = ((c*2+half)*4+quad)*16+dimlr, j=key-perm.
// ============================================================
template<int F32>
__global__ __launch_bounds__(256) void ln_qkv_mfma(
    const void* __restrict__ xin, const void* __restrict__ rmask,
    const void* __restrict__ wi, const void* __restrict__ gamma,
    const void* __restrict__ beta,
    u16* __restrict__ qbuf, u16* __restrict__ kbuf, u16* __restrict__ vt)
{
  if (sniff_mode(xin) != F32) return;

  __shared__ __align__(16) u16 XnF[2 * 8 * 64 * 8];   // 16 KB
  __shared__ float lmr[32];
  const int tid = threadIdx.x;
  const int l = tid & 63, w = tid >> 6;
  const int lr = l & 15, quad = l >> 4;
  const int row0 = (blockIdx.x >> 1) * 32;
  const int nhalf = blockIdx.x & 1;

  // ---- Phase A: LayerNorm, frag-major store ----
  {
    const int r = tid >> 5, ln = tid & 31;
    float g[8], bb[8];
    load8<F32>(gamma, ln, g);
    load8<F32>(beta,  ln, bb);
    const int c = ln >> 2, qd = ln & 3;
#pragma unroll
    for (int p = 0; p < 4; ++p) {
      const int R = p * 8 + r;
      const int grow = row0 + R;
      float x[8]; load8<F32>(xin, grow * 32 + ln, x);
      float s = 0.f, sq = 0.f;
#pragma unroll
      for (int j = 0; j < 8; ++j) { s += x[j]; sq += x[j] * x[j]; }
#pragma unroll
      for (int m = 1; m < 32; m <<= 1) { s += __shfl_xor(s, m); sq += __shfl_xor(sq, m); }
      const float mu  = s * (1.f / 256.f);
      const float var = sq * (1.f / 256.f) - mu * mu;
      const float rs  = rsqrtf(var + 1e-5f);
      short8 pk;
#pragma unroll
      for (int j = 0; j < 8; ++j) pk[j] = (short)f2b((x[j] - mu) * rs * g[j] + bb[j]);
      const int t = R >> 4, rm = R & 15;
      *(short8*)(XnF + (((t * 8 + c) * 64 + qd * 16 + rm) << 3)) = pk;
      if (ln == 0) lmr[R] = logf(load1<F32>(rmask, grow));
    }
  }
  __syncthreads();

  // ---- Phase B: GEMM, 6 n-tiles/wave, double-buffered B-frags ----
  const int bb_ = row0 >> 9;
  const int sB  = (row0 & 511);
  const int tbase = nhalf * 24 + w * 6;

  short8 BfA[8], BfB[8];
#pragma unroll
  for (int c = 0; c < 8; ++c)
    BfA[c] = loadBfrag<F32>(wi, tbase * 16 + lr, c * 32 + quad * 8, 256);

#pragma unroll
  for (int nt = 0; nt < 6; ++nt) {
    short8* cur = (nt & 1) ? BfB : BfA;
    short8* nxt = (nt & 1) ? BfA : BfB;
    if (nt < 5) {
#pragma unroll
      for (int c = 0; c < 8; ++c)
        nxt[c] = loadBfrag<F32>(wi, (tbase + nt + 1) * 16 + lr, c * 32 + quad * 8, 256);
    }

    f32x4 a0 = {0.f,0.f,0.f,0.f}, a1 = {0.f,0.f,0.f,0.f};
#pragma unroll
    for (int c = 0; c < 8; ++c) {
      const short8 f0 = *(const short8*)(XnF + ((c       * 64 + l) << 3));
      const short8 f1 = *(const short8*)(XnF + (((8 + c) * 64 + l) << 3));
      a0 = mfma16(f0, cur[c], a0);
      a1 = mfma16(f1, cur[c], a1);
    }

    const int nAbs = (tbase + nt) * 16;
    const int type = nAbs >> 8;              // 0=q 1=k 2=v
    const int d    = (nAbs & 255) + lr;
    const int h    = d >> 5, dd = d & 31;
    const int bh   = bb_ * NH_ + h;
#pragma unroll
    for (int m = 0; m < 2; ++m) {
      const f32x4 acc = m ? a1 : a0;
      const int sLoc = m * 16 + quad * 4;
      if (type == 0) {
#pragma unroll
        for (int i = 0; i < 4; ++i) {
          float qv = acc[i]; qv = qv * qv + 1e-6f;
          qbuf[((size_t)bh * S_ + (sB + sLoc + i)) * HD_ + dd] = f2b(qv);
        }
      } else if (type == 1) {
#pragma unroll
        for (int i = 0; i < 4; ++i)
          kbuf[((size_t)bh * S_ + (sB + sLoc + i)) * HD_ + dd] = f2b(acc[i] + lmr[sLoc + i]);
      } else {
        // sigma-permuted V: key_local = m*16+quad*4+i -> j = m*4+i, q_pos=quad
        const int slot16 = (((sB >> 5) * 2 + (dd >> 4)) * 4 + quad) * 16 + (dd & 15);
        uint2 pkv;
        pkv.x = pk2(acc[0], acc[1]);
        pkv.y = pk2(acc[2], acc[3]);
        *(uint2*)(vt + (size_t)bh * (S_ * HD_) + slot16 * 8 + m * 4) = pkv;
      }
    }
  }
}

// ============================================================
// Kernel 2: LDS-free MFMA flash attention, zero-shuffle P transform.
// Grid 2048 = (sq 0..7)*256 + bh (XCD swizzle). 4 waves x 16 queries.
// V is sigma-key-permuted so P's C-layout acc IS the A-frag directly.
// ============================================================
__global__ __launch_bounds__(256) void attn_mfma(
    const u16* __restrict__ qbuf, const u16* __restrict__ kbuf,
    const u16* __restrict__ vt, u16* __restrict__ ctx)
{
  __shared__ __align__(16) u16 OB[4][16 * 40];   // wave-private out transpose (5 KB)
  const int tid = threadIdx.x;
  const int bh = blockIdx.x & 255, sq = blockIdx.x >> 8;
  const int l = tid & 63, w = tid >> 6;
  const int lr = l & 15, quad = l >> 4;
  const size_t kvbase = (size_t)bh * (S_ * HD_);
  const int q0 = sq * 64 + w * 16;

  const float cE = 0.17677669529663688f * 1.4426950408889634f; // (1/sqrt(32))*log2(e)

  // B-frag: Q[q0+lr][quad*8..+7]
  const short8 qf = *(const short8*)(qbuf + kvbase + (size_t)(q0 + lr) * HD_ + quad * 8);

  // ---- QK^T: acc[kt] holds S^T[key=16kt+quad*4+r][query=lr] ----
  const u16* kp = kbuf + kvbase + (size_t)lr * HD_ + quad * 8;
  f32x4 acc[32];
#pragma unroll
  for (int kt = 0; kt < 32; ++kt) {
    const short8 kf = *(const short8*)(kp + kt * (16 * HD_));
    f32x4 z = {0.f, 0.f, 0.f, 0.f};
    acc[kt] = mfma16(kf, qf, z);
  }

  // ---- softmax over keys for query col=lr ----
  float mx = -1e30f;
#pragma unroll
  for (int kt = 0; kt < 32; ++kt) {
#pragma unroll
    for (int r = 0; r < 4; ++r) mx = fmaxf(mx, acc[kt][r]);
  }
  mx = fmaxf(mx, __shfl_xor(mx, 16));
  mx = fmaxf(mx, __shfl_xor(mx, 32));
  const float mE = mx * cE;
  float sum = 0.f;
#pragma unroll
  for (int kt = 0; kt < 32; ++kt) {
#pragma unroll
    for (int r = 0; r < 4; ++r) {
      const float p = exp2f(fmaf(acc[kt][r], cE, -mE));
      acc[kt][r] = p; sum += p;
    }
  }
  sum += __shfl_xor(sum, 16);
  sum += __shfl_xor(sum, 32);
  const float inv = 1.f / sum;

  // ---- PV: A-frag = own acc (sigma-permuted keys), V direct from global ----
  const u16* vp = vt + kvbase;
  f32x4 o0 = {0.f,0.f,0.f,0.f}, o1 = {0.f,0.f,0.f,0.f};
#pragma unroll
  for (int c = 0; c < 16; ++c) {
    union { u32 u[4]; short8 s; } pa;
    pa.u[0] = pk2(acc[2*c][0],   acc[2*c][1]);
    pa.u[1] = pk2(acc[2*c][2],   acc[2*c][3]);
    pa.u[2] = pk2(acc[2*c+1][0], acc[2*c+1][1]);
    pa.u[3] = pk2(acc[2*c+1][2], acc[2*c+1][3]);
    const short8 v0 = *(const short8*)(vp + (((c * 8 +     quad) * 16 + lr) << 3));
    const short8 v1 = *(const short8*)(vp + (((c * 8 + 4 + quad) * 16 + lr) << 3));
    o0 = mfma16(pa.s, v0, o0);
    o1 = mfma16(pa.s, v1, o1);
  }

  // ---- epilogue: scale, wave-private LDS transpose, coalesced 16B store ----
  u16* ob = OB[w];
#pragma unroll
  for (int r = 0; r < 4; ++r) {
    const int qq = quad * 4 + r;
    const float iv = __shfl(inv, (l & 48) | qq);
    ob[qq * 40 + lr]      = f2b(o0[r] * iv);
    ob[qq * 40 + 16 + lr] = f2b(o1[r] * iv);
  }
  const uint4 ov = *(const uint4*)(ob + (l >> 2) * 40 + (l & 3) * 8);
  *(uint4*)(ctx + kvbase + (size_t)(q0 + (l >> 2)) * HD_ + (l & 3) * 8) = ov;
}

// ============================================================
// Kernel 3: out-proj via MFMA + residual + sqrt(1/2).
// ctx layout [bh][s][hd]. Coalesced out stores via LDS result tile.
// ============================================================
template<int F32>
__global__ __launch_bounds__(256) void proj_mfma(
    const u16* __restrict__ ctx, const void* __restrict__ xin,
    const void* __restrict__ wo, void* __restrict__ out)
{
  if (sniff_mode(xin) != F32) return;

  __shared__ __align__(16) u16 XnF[2 * 8 * 64 * 8];   // 16 KB
  __shared__ __align__(16) u16 OutB[32 * 264];        // 16.5 KB
  const int tid = threadIdx.x;
  const int l = tid & 63, w = tid >> 6;
  const int lr = l & 15, quad = l >> 4;
  const int row0 = blockIdx.x * 32;
  const int b = row0 >> 9, s0 = row0 & 511;

  // ---- stage ctx -> A-frag LDS (swizzled: qd' = qd ^ (rm&3)) ----
#pragma unroll
  for (int it = 0; it < 4; ++it) {
    const int idx = it * 256 + tid;
    const int dq = idx & 3, sl = (idx >> 2) & 31, h = idx >> 7;
    const uint4 cv = *(const uint4*)(ctx + ((size_t)(b * 8 + h) * S_ + s0 + sl) * HD_ + dq * 8);
    const int t = sl >> 4, rm = sl & 15;
    const int qds = dq ^ (rm & 3);
    *(uint4*)(XnF + (((t * 8 + h) * 64 + qds * 16 + rm) << 3)) = cv;
  }
  __syncthreads();

  const int lsw = (quad ^ (lr & 3)) * 16 + lr;   // swizzled A-frag read slot
  for (int nt = 0; nt < 4; ++nt) {
    const int n0 = (w * 4 + nt) * 16;
    short8 Bf[8];
#pragma unroll
    for (int c = 0; c < 8; ++c) Bf[c] = loadBfrag<F32>(wo, n0 + lr, c * 32 + quad * 8, 256);

    f32x4 a0 = {0.f,0.f,0.f,0.f}, a1 = {0.f,0.f,0.f,0.f};
#pragma unroll
    for (int c = 0; c < 8; ++c) {
      const short8 f0 = *(const short8*)(XnF + ((c       * 64 + lsw) << 3));
      const short8 f1 = *(const short8*)(XnF + (((8 + c) * 64 + lsw) << 3));
      a0 = mfma16(f0, Bf[c], a0);
      a1 = mfma16(f1, Bf[c], a1);
    }

#pragma unroll
    for (int m = 0; m < 2; ++m) {
      const f32x4 acc = m ? a1 : a0;
#pragma unroll
      for (int i = 0; i < 4; ++i)
        OutB[(m * 16 + quad * 4 + i) * 264 + n0 + lr] = f2b(acc[i]);
    }
  }
  __syncthreads();

  // ---- epilogue: residual + scale, vectorized coalesced store ----
  const int r  = tid >> 3;
  const int c8 = (tid & 7) * 4;
#pragma unroll
  for (int j8 = 0; j8 < 4; ++j8) {
    float xv[8]; load8<F32>(xin, (row0 + r) * 32 + c8 + j8, xv);
    float pv[8]; unp8(*(const uint4*)(OutB + r * 264 + (c8 + j8) * 8), pv);
    float ov[8];
#pragma unroll
    for (int j = 0; j < 8; ++j) ov[j] = (pv[j] + xv[j]) * 0.70710678f;
    store8<F32>(out, (row0 + r) * 32 + c8 + j8, ov);
  }
}

// ============================================================
extern "C" void kernel_launch(void* const* d_in, const int* in_sizes, int n_in,
                              void* d_out, int out_size, void* d_ws, size_t ws_size,
                              hipStream_t stream)
{
  const void* xin   = d_in[0];
  const void* rmask = d_in[1];
  const void* wi    = d_in[2];
  const void* wo    = d_in[3];
  const void* gam   = d_in[4];
  const void* bet   = d_in[5];

  u16* q   = (u16*)d_ws;                   // [256][512][32] bf16 (8 MB)
  u16* k   = q + 4194304;
  u16* vt  = k + 4194304;                  // sigma-permuted V (8 MB)
  u16* cxb = vt + 4194304;                 // ctx [bh][s][hd] bf16 (8 MB)

  ln_qkv_mfma<0><<<1024, 256, 0, stream>>>(xin, rmask, wi, gam, bet, q, k, vt);
  ln_qkv_mfma<1><<<1024, 256, 0, stream>>>(xin, rmask, wi, gam, bet, q, k, vt);
  attn_mfma     <<<2048, 256, 0, stream>>>(q, k, vt, cxb);
  proj_mfma<0>  <<<512,  256, 0, stream>>>(cxb, xin, wo, d_out);
  proj_mfma<1>  <<<512,  256, 0, stream>>>(cxb, xin, wo, d_out);
}

// Round 8
// 204.623 us; speedup vs baseline: 1.1847x; 1.0445x over previous
//
#include <hip/hip_runtime.h>
#include <hip/hip_bf16.h>

typedef unsigned int u32;
typedef unsigned short u16;

#define B_   32
#define S_   512
#define H_   256
#define NH_  8
#define HD_  32

typedef __attribute__((ext_vector_type(8))) short short8;
typedef __attribute__((ext_vector_type(4))) float f32x4;

// ---------- bf16 helpers ----------
__device__ __forceinline__ float bfl(u32 u){ union{u32 i;float f;} c; c.i = u << 16;          return c.f; }
__device__ __forceinline__ float bfh(u32 u){ union{u32 i;float f;} c; c.i = u & 0xffff0000u;  return c.f; }
__device__ __forceinline__ float bf1(u16 u){ union{u32 i;float f;} c; c.i = ((u32)u) << 16;   return c.f; }
__device__ __forceinline__ u16   f2b(float f){ __hip_bfloat16 h = __float2bfloat16(f); return *reinterpret_cast<u16*>(&h); }
__device__ __forceinline__ u32   pk2(float a, float b){ return (u32)f2b(a) | ((u32)f2b(b) << 16); }
__device__ __forceinline__ void  unp8(const uint4 u, float* f){
  f[0]=bfl(u.x); f[1]=bfh(u.x); f[2]=bfl(u.y); f[3]=bfh(u.y);
  f[4]=bfl(u.z); f[5]=bfh(u.z); f[6]=bfl(u.w); f[7]=bfh(u.w);
}
__device__ __forceinline__ f32x4 mfma16(short8 a, short8 b, f32x4 c){
  return __builtin_amdgcn_mfma_f32_16x16x32_bf16(a, b, c, 0, 0, 0);
}

// ---------- dtype-polymorphic loads/stores ----------
template<int F32>
__device__ __forceinline__ void load8(const void* p, int e8, float* f) {
  if (F32) {
    const float4* q = (const float4*)p;
    const float4 a = q[e8 * 2], b = q[e8 * 2 + 1];
    f[0]=a.x; f[1]=a.y; f[2]=a.z; f[3]=a.w; f[4]=b.x; f[5]=b.y; f[6]=b.z; f[7]=b.w;
  } else {
    unp8(((const uint4*)p)[e8], f);
  }
}
template<int F32>
__device__ __forceinline__ void store8(void* p, int e8, const float* f) {
  if (F32) {
    float4* q = (float4*)p;
    q[e8 * 2]     = make_float4(f[0], f[1], f[2], f[3]);
    q[e8 * 2 + 1] = make_float4(f[4], f[5], f[6], f[7]);
  } else {
    uint4 u;
    u.x = pk2(f[0], f[1]); u.y = pk2(f[2], f[3]);
    u.z = pk2(f[4], f[5]); u.w = pk2(f[6], f[7]);
    ((uint4*)p)[e8] = u;
  }
}
template<int F32>
__device__ __forceinline__ float load1(const void* p, size_t e) {
  return F32 ? ((const float*)p)[e] : bf1(((const u16*)p)[e]);
}
template<int F32>
__device__ __forceinline__ short8 loadBfrag(const void* wp, int row, int k0, int K) {
  if (F32) {
    const float* w = (const float*)wp + (size_t)row * K + k0;
    const float4 a = *(const float4*)w;
    const float4 b = *(const float4*)(w + 4);
    short8 r;
    r[0]=(short)f2b(a.x); r[1]=(short)f2b(a.y); r[2]=(short)f2b(a.z); r[3]=(short)f2b(a.w);
    r[4]=(short)f2b(b.x); r[5]=(short)f2b(b.y); r[6]=(short)f2b(b.z); r[7]=(short)f2b(b.w);
    return r;
  } else {
    return *(const short8*)((const u16*)wp + (size_t)row * K + k0);
  }
}

// ---------- dtype sniff (first 4KB of `inputs`) ----------
__device__ __forceinline__ int sniff_mode(const void* xin) {   // 0=bf16, 1=f32
  __shared__ int votes;
  const int tid = threadIdx.x;
  if (tid == 0) votes = 0;
  __syncthreads();
  const u32* xw = (const u32*)xin;
  int h = 0;
#pragma unroll
  for (int j = 0; j < 4; ++j) {
    const u32 u = xw[(tid << 2) + j];
    const u32 e = (u >> 7) & 0xFF;
    h += (e >= 100 && e <= 135) ? 1 : 0;
  }
  if (h) atomicAdd(&votes, h);
  __syncthreads();
  return (votes >= 512) ? 0 : 1;
}

// ============================================================
// Kernel 1: LN + QKV via MFMA. Grid 1024 = m-block x nhalf.
// q/k stores: wave-private LDS transpose -> 1 dwordx4/tile.
// v: sigma-permuted attn B-frag order.
// ============================================================
template<int F32>
__global__ __launch_bounds__(256) void ln_qkv_mfma(
    const void* __restrict__ xin, const void* __restrict__ rmask,
    const void* __restrict__ wi, const void* __restrict__ gamma,
    const void* __restrict__ beta,
    u16* __restrict__ qbuf, u16* __restrict__ kbuf, u16* __restrict__ vt)
{
  if (sniff_mode(xin) != F32) return;

  __shared__ __align__(16) u16 XnF[2 * 8 * 64 * 8];   // 16 KB
  __shared__ __align__(16) u16 TR[4][32 * 20];        // 5 KB wave-private transpose
  __shared__ float lmr[32];
  const int tid = threadIdx.x;
  const int l = tid & 63, w = tid >> 6;
  const int lr = l & 15, quad = l >> 4;
  const int row0 = (blockIdx.x >> 1) * 32;
  const int nhalf = blockIdx.x & 1;

  // ---- Phase A: LayerNorm, frag-major store ----
  {
    const int r = tid >> 5, ln = tid & 31;
    float g[8], bb[8];
    load8<F32>(gamma, ln, g);
    load8<F32>(beta,  ln, bb);
    const int c = ln >> 2, qd = ln & 3;
#pragma unroll
    for (int p = 0; p < 4; ++p) {
      const int R = p * 8 + r;
      const int grow = row0 + R;
      float x[8]; load8<F32>(xin, grow * 32 + ln, x);
      float s = 0.f, sq = 0.f;
#pragma unroll
      for (int j = 0; j < 8; ++j) { s += x[j]; sq += x[j] * x[j]; }
#pragma unroll
      for (int m = 1; m < 32; m <<= 1) { s += __shfl_xor(s, m); sq += __shfl_xor(sq, m); }
      const float mu  = s * (1.f / 256.f);
      const float var = sq * (1.f / 256.f) - mu * mu;
      const float rs  = rsqrtf(var + 1e-5f);
      short8 pk;
#pragma unroll
      for (int j = 0; j < 8; ++j) pk[j] = (short)f2b((x[j] - mu) * rs * g[j] + bb[j]);
      const int t = R >> 4, rm = R & 15;
      *(short8*)(XnF + (((t * 8 + c) * 64 + qd * 16 + rm) << 3)) = pk;
      if (ln == 0) lmr[R] = logf(load1<F32>(rmask, grow));
    }
  }
  __syncthreads();

  // ---- Phase B: GEMM, 6 n-tiles/wave, double-buffered B-frags ----
  const int bb_ = row0 >> 9;
  const int sB  = (row0 & 511);
  const int tbase = nhalf * 24 + w * 6;
  u16* trw = TR[w];

  short8 BfA[8], BfB[8];
#pragma unroll
  for (int c = 0; c < 8; ++c)
    BfA[c] = loadBfrag<F32>(wi, tbase * 16 + lr, c * 32 + quad * 8, 256);

#pragma unroll
  for (int nt = 0; nt < 6; ++nt) {
    short8* cur = (nt & 1) ? BfB : BfA;
    short8* nxt = (nt & 1) ? BfA : BfB;
    if (nt < 5) {
#pragma unroll
      for (int c = 0; c < 8; ++c)
        nxt[c] = loadBfrag<F32>(wi, (tbase + nt + 1) * 16 + lr, c * 32 + quad * 8, 256);
    }

    f32x4 a0 = {0.f,0.f,0.f,0.f}, a1 = {0.f,0.f,0.f,0.f};
#pragma unroll
    for (int c = 0; c < 8; ++c) {
      const short8 f0 = *(const short8*)(XnF + ((c       * 64 + l) << 3));
      const short8 f1 = *(const short8*)(XnF + (((8 + c) * 64 + l) << 3));
      a0 = mfma16(f0, cur[c], a0);
      a1 = mfma16(f1, cur[c], a1);
    }

    const int nAbs  = (tbase + nt) * 16;
    const int type  = nAbs >> 8;              // 0=q 1=k 2=v
    const int dbase = nAbs & 255;
    const int bh    = bb_ * NH_ + (dbase >> 5);
    if (type < 2) {
      // ---- wave-private LDS transpose -> coalesced dwordx4 store ----
#pragma unroll
      for (int m = 0; m < 2; ++m) {
        const f32x4 acc = m ? a1 : a0;
        const int sL = m * 16 + quad * 4;
#pragma unroll
        for (int i = 0; i < 4; ++i) {
          float v = acc[i];
          v = (type == 0) ? (v * v + 1e-6f) : (v + lmr[sL + i]);
          trw[(sL + i) * 20 + lr] = f2b(v);
        }
      }
      const int s = l >> 1, half = l & 1;
      const uint2 lo = *(const uint2*)(trw + s * 20 + half * 8);
      const uint2 hi = *(const uint2*)(trw + s * 20 + half * 8 + 4);
      uint4 ov; ov.x = lo.x; ov.y = lo.y; ov.z = hi.x; ov.w = hi.y;
      u16* dst = (type == 0) ? qbuf : kbuf;
      *(uint4*)(dst + ((size_t)bh * S_ + sB + s) * HD_ + (dbase & 31) + half * 8) = ov;
    } else {
      const int dd = (dbase & 255) + lr;   // 512..: dd within v block
#pragma unroll
      for (int m = 0; m < 2; ++m) {
        const f32x4 acc = m ? a1 : a0;
        const int dv = (dbase - 512 + lr) & 255;   // v-dim 0..255
        const int hv = dv >> 5, ddv = dv & 31;
        const int bhv = bb_ * NH_ + hv;
        const int slot16 = (((sB >> 5) * 2 + (ddv >> 4)) * 4 + quad) * 16 + (ddv & 15);
        uint2 pkv;
        pkv.x = pk2(acc[0], acc[1]);
        pkv.y = pk2(acc[2], acc[3]);
        *(uint2*)(vt + (size_t)bhv * (S_ * HD_) + slot16 * 8 + m * 4) = pkv;
      }
      (void)dd;
    }
  }
}

// ============================================================
// Kernel 2: LDS-free flash attention, online softmax in 4 chunks
// of 128 keys (acc[8] live -> low VGPR, 4+ waves/SIMD).
// Grid 2048 = (sq)*256 + bh (XCD swizzle). V sigma-key-permuted.
// ============================================================
__global__ __launch_bounds__(256, 4) void attn_mfma(
    const u16* __restrict__ qbuf, const u16* __restrict__ kbuf,
    const u16* __restrict__ vt, u16* __restrict__ ctx)
{
  __shared__ __align__(16) u16 OB[4][16 * 40];   // wave-private out transpose (5 KB)
  const int tid = threadIdx.x;
  const int bh = blockIdx.x & 255, sq = blockIdx.x >> 8;
  const int l = tid & 63, w = tid >> 6;
  const int lr = l & 15, quad = l >> 4;
  const size_t kvbase = (size_t)bh * (S_ * HD_);
  const int q0 = sq * 64 + w * 16;

  const float cE = 0.17677669529663688f * 1.4426950408889634f; // (1/sqrt(32))*log2(e)

  const short8 qf = *(const short8*)(qbuf + kvbase + (size_t)(q0 + lr) * HD_ + quad * 8);
  const u16* kp = kbuf + kvbase + (size_t)lr * HD_ + quad * 8;
  const u16* vp = vt + kvbase;

  float mS = -1e30f, lS = 0.f;
  f32x4 o0 = {0.f,0.f,0.f,0.f}, o1 = {0.f,0.f,0.f,0.f};

#pragma unroll
  for (int c = 0; c < 4; ++c) {
    // ---- QK^T chunk: keys c*128 .. +127 ----
    f32x4 acc[8];
#pragma unroll
    for (int j = 0; j < 8; ++j) {
      const short8 kf = *(const short8*)(kp + (c * 8 + j) * (16 * HD_));
      f32x4 z = {0.f,0.f,0.f,0.f};
      acc[j] = mfma16(kf, qf, z);
    }

    // ---- online softmax update (per query col=lr) ----
    float mc = acc[0][0];
#pragma unroll
    for (int j = 0; j < 8; ++j)
#pragma unroll
      for (int r = 0; r < 4; ++r) mc = fmaxf(mc, acc[j][r]);
    mc = fmaxf(mc, __shfl_xor(mc, 16));
    mc = fmaxf(mc, __shfl_xor(mc, 32));
    const float mNew  = fmaxf(mS, mc * cE);
    const float alpha = exp2f(mS - mNew);
    float sc = 0.f;
#pragma unroll
    for (int j = 0; j < 8; ++j)
#pragma unroll
      for (int r = 0; r < 4; ++r) {
        const float p = exp2f(fmaf(acc[j][r], cE, -mNew));
        acc[j][r] = p; sc += p;
      }
    sc += __shfl_xor(sc, 16);
    sc += __shfl_xor(sc, 32);
    lS = fmaf(lS, alpha, sc);
    mS = mNew;
#pragma unroll
    for (int r = 0; r < 4; ++r) { o0[r] *= alpha; o1[r] *= alpha; }

    // ---- PV chunk: A-frag = own acc (sigma-permuted keys) ----
#pragma unroll
    for (int g = 0; g < 4; ++g) {
      union { u32 u[4]; short8 s; } pa;
      pa.u[0] = pk2(acc[2*g][0],   acc[2*g][1]);
      pa.u[1] = pk2(acc[2*g][2],   acc[2*g][3]);
      pa.u[2] = pk2(acc[2*g+1][0], acc[2*g+1][1]);
      pa.u[3] = pk2(acc[2*g+1][2], acc[2*g+1][3]);
      const int c16 = c * 4 + g;
      const short8 v0 = *(const short8*)(vp + (((c16 * 8 +     quad) * 16 + lr) << 3));
      const short8 v1 = *(const short8*)(vp + (((c16 * 8 + 4 + quad) * 16 + lr) << 3));
      o0 = mfma16(pa.s, v0, o0);
      o1 = mfma16(pa.s, v1, o1);
    }
  }
  const float inv = 1.f / lS;

  // ---- epilogue: scale, wave-private LDS transpose, coalesced 16B store ----
  u16* ob = OB[w];
#pragma unroll
  for (int r = 0; r < 4; ++r) {
    const int qq = quad * 4 + r;
    const float iv = __shfl(inv, (l & 48) | qq);
    ob[qq * 40 + lr]      = f2b(o0[r] * iv);
    ob[qq * 40 + 16 + lr] = f2b(o1[r] * iv);
  }
  const uint4 ov = *(const uint4*)(ob + (l >> 2) * 40 + (l & 3) * 8);
  *(uint4*)(ctx + kvbase + (size_t)(q0 + (l >> 2)) * HD_ + (l & 3) * 8) = ov;
}

// ============================================================
// Kernel 3: out-proj via MFMA + residual + sqrt(1/2).
// Grid 1024 (M=16), B-frag prefetch dbuf, coalesced stores.
// ============================================================
template<int F32>
__global__ __launch_bounds__(256) void proj_mfma(
    const u16* __restrict__ ctx, const void* __restrict__ xin,
    const void* __restrict__ wo, void* __restrict__ out)
{
  if (sniff_mode(xin) != F32) return;

  __shared__ __align__(16) u16 XnF[8 * 64 * 8];   // 8 KB (one m-tile)
  __shared__ __align__(16) u16 OutB[16 * 264];    // 8.25 KB
  const int tid = threadIdx.x;
  const int l = tid & 63, w = tid >> 6;
  const int lr = l & 15, quad = l >> 4;
  const int row0 = blockIdx.x * 16;
  const int b = row0 >> 9, s0 = row0 & 511;

  // ---- stage ctx -> A-frag LDS (swizzled) ----
#pragma unroll
  for (int it = 0; it < 2; ++it) {
    const int idx = it * 256 + tid;          // 0..511 : 16 rows x 32 uint4
    const int dq = idx & 3, sl = (idx >> 2) & 15, h = idx >> 6;
    const uint4 cv = *(const uint4*)(ctx + ((size_t)(b * 8 + h) * S_ + s0 + sl) * HD_ + dq * 8);
    const int qds = dq ^ (sl & 3);
    *(uint4*)(XnF + ((h * 64 + qds * 16 + sl) << 3)) = cv;
  }
  __syncthreads();

  const int lsw = (quad ^ (lr & 3)) * 16 + lr;
  short8 BfA[8], BfB[8];
#pragma unroll
  for (int c = 0; c < 8; ++c)
    BfA[c] = loadBfrag<F32>(wo, (w * 4) * 16 + lr, c * 32 + quad * 8, 256);

#pragma unroll
  for (int nt = 0; nt < 4; ++nt) {
    short8* cur = (nt & 1) ? BfB : BfA;
    short8* nxt = (nt & 1) ? BfA : BfB;
    if (nt < 3) {
#pragma unroll
      for (int c = 0; c < 8; ++c)
        nxt[c] = loadBfrag<F32>(wo, (w * 4 + nt + 1) * 16 + lr, c * 32 + quad * 8, 256);
    }
    const int n0 = (w * 4 + nt) * 16;
    f32x4 a0 = {0.f,0.f,0.f,0.f};
#pragma unroll
    for (int c = 0; c < 8; ++c) {
      const short8 f0 = *(const short8*)(XnF + ((c * 64 + lsw) << 3));
      a0 = mfma16(f0, cur[c], a0);
    }
#pragma unroll
    for (int i = 0; i < 4; ++i)
      OutB[(quad * 4 + i) * 264 + n0 + lr] = f2b(a0[i]);
  }
  __syncthreads();

  // ---- epilogue: residual + scale, vectorized coalesced store ----
  const int r  = tid >> 4;             // 0..15
  const int c8 = (tid & 15) * 2;       // e8 base within row
#pragma unroll
  for (int j8 = 0; j8 < 2; ++j8) {
    float xv[8]; load8<F32>(xin, (row0 + r) * 32 + c8 + j8, xv);
    float pv[8]; unp8(*(const uint4*)(OutB + r * 264 + (c8 + j8) * 8), pv);
    float ov[8];
#pragma unroll
    for (int j = 0; j < 8; ++j) ov[j] = (pv[j] + xv[j]) * 0.70710678f;
    store8<F32>(out, (row0 + r) * 32 + c8 + j8, ov);
  }
}

// ============================================================
extern "C" void kernel_launch(void* const* d_in, const int* in_sizes, int n_in,
                              void* d_out, int out_size, void* d_ws, size_t ws_size,
                              hipStream_t stream)
{
  const void* xin   = d_in[0];
  const void* rmask = d_in[1];
  const void* wi    = d_in[2];
  const void* wo    = d_in[3];
  const void* gam   = d_in[4];
  const void* bet   = d_in[5];

  u16* q   = (u16*)d_ws;                   // [256][512][32] bf16 (8 MB)
  u16* k   = q + 4194304;
  u16* vt  = k + 4194304;                  // sigma-permuted V (8 MB)
  u16* cxb = vt + 4194304;                 // ctx [bh][s][hd] bf16 (8 MB)

  ln_qkv_mfma<0><<<1024, 256, 0, stream>>>(xin, rmask, wi, gam, bet, q, k, vt);
  ln_qkv_mfma<1><<<1024, 256, 0, stream>>>(xin, rmask, wi, gam, bet, q, k, vt);
  attn_mfma     <<<2048, 256, 0, stream>>>(q, k, vt, cxb);
  proj_mfma<0>  <<<1024, 256, 0, stream>>>(cxb, xin, wo, d_out);
  proj_mfma<1>  <<<1024, 256, 0, stream>>>(cxb, xin, wo, d_out);
}

// Round 9
// 181.029 us; speedup vs baseline: 1.3391x; 1.1303x over previous
//
#include <hip/hip_runtime.h>
#include <hip/hip_bf16.h>

typedef unsigned int u32;
typedef unsigned short u16;

#define B_   32
#define S_   512
#define H_   256
#define NH_  8
#define HD_  32

typedef __attribute__((ext_vector_type(8))) short short8;
typedef __attribute__((ext_vector_type(4))) float f32x4;

// ---------- bf16 helpers ----------
__device__ __forceinline__ float bfl(u32 u){ union{u32 i;float f;} c; c.i = u << 16;          return c.f; }
__device__ __forceinline__ float bfh(u32 u){ union{u32 i;float f;} c; c.i = u & 0xffff0000u;  return c.f; }
__device__ __forceinline__ float bf1(u16 u){ union{u32 i;float f;} c; c.i = ((u32)u) << 16;   return c.f; }
__device__ __forceinline__ u16   f2b(float f){ __hip_bfloat16 h = __float2bfloat16(f); return *reinterpret_cast<u16*>(&h); }
__device__ __forceinline__ u32   pk2(float a, float b){ return (u32)f2b(a) | ((u32)f2b(b) << 16); }
__device__ __forceinline__ void  unp8(const uint4 u, float* f){
  f[0]=bfl(u.x); f[1]=bfh(u.x); f[2]=bfl(u.y); f[3]=bfh(u.y);
  f[4]=bfl(u.z); f[5]=bfh(u.z); f[6]=bfl(u.w); f[7]=bfh(u.w);
}
__device__ __forceinline__ f32x4 mfma16(short8 a, short8 b, f32x4 c){
  return __builtin_amdgcn_mfma_f32_16x16x32_bf16(a, b, c, 0, 0, 0);
}

// ---------- dtype-polymorphic loads/stores ----------
template<int F32>
__device__ __forceinline__ void load8(const void* p, int e8, float* f) {
  if (F32) {
    const float4* q = (const float4*)p;
    const float4 a = q[e8 * 2], b = q[e8 * 2 + 1];
    f[0]=a.x; f[1]=a.y; f[2]=a.z; f[3]=a.w; f[4]=b.x; f[5]=b.y; f[6]=b.z; f[7]=b.w;
  } else {
    unp8(((const uint4*)p)[e8], f);
  }
}
template<int F32>
__device__ __forceinline__ void store8(void* p, int e8, const float* f) {
  if (F32) {
    float4* q = (float4*)p;
    q[e8 * 2]     = make_float4(f[0], f[1], f[2], f[3]);
    q[e8 * 2 + 1] = make_float4(f[4], f[5], f[6], f[7]);
  } else {
    uint4 u;
    u.x = pk2(f[0], f[1]); u.y = pk2(f[2], f[3]);
    u.z = pk2(f[4], f[5]); u.w = pk2(f[6], f[7]);
    ((uint4*)p)[e8] = u;
  }
}
template<int F32>
__device__ __forceinline__ float load1(const void* p, size_t e) {
  return F32 ? ((const float*)p)[e] : bf1(((const u16*)p)[e]);
}
template<int F32>
__device__ __forceinline__ short8 loadBfrag(const void* wp, int row, int k0, int K) {
  if (F32) {
    const float* w = (const float*)wp + (size_t)row * K + k0;
    const float4 a = *(const float4*)w;
    const float4 b = *(const float4*)(w + 4);
    short8 r;
    r[0]=(short)f2b(a.x); r[1]=(short)f2b(a.y); r[2]=(short)f2b(a.z); r[3]=(short)f2b(a.w);
    r[4]=(short)f2b(b.x); r[5]=(short)f2b(b.y); r[6]=(short)f2b(b.z); r[7]=(short)f2b(b.w);
    return r;
  } else {
    return *(const short8*)((const u16*)wp + (size_t)row * K + k0);
  }
}

// ---------- dtype sniff (first 4KB of `inputs`), one atomic per wave ----------
__device__ __forceinline__ int sniff_mode(const void* xin) {   // 0=bf16, 1=f32
  __shared__ int votes;
  const int tid = threadIdx.x;
  if (tid == 0) votes = 0;
  __syncthreads();
  const u32* xw = (const u32*)xin;
  int h = 0;
#pragma unroll
  for (int j = 0; j < 4; ++j) {
    const u32 u = xw[(tid << 2) + j];
    const u32 e = (u >> 7) & 0xFF;
    h += (e >= 100 && e <= 135) ? 1 : 0;
  }
  const unsigned long long m = __ballot(h >= 3);
  if ((tid & 63) == 0) atomicAdd(&votes, __popcll(m));
  __syncthreads();
  return (votes >= 128) ? 0 : 1;
}

// ============================================================
// Kernel 1: LN + QKV via MFMA. Grid 512 = (m-superblock 64 rows) x nhalf.
// A-fragments register-resident across all 6 n-tiles; B-frag dbuf with
// constant indices (register-guaranteed). q,k: [bh][s][d] scalar stores.
// v: sigma-permuted attn B-frag order.
// ============================================================
template<int F32>
__global__ __launch_bounds__(256, 2) void ln_qkv_mfma(
    const void* __restrict__ xin, const void* __restrict__ rmask,
    const void* __restrict__ wi, const void* __restrict__ gamma,
    const void* __restrict__ beta,
    u16* __restrict__ qbuf, u16* __restrict__ kbuf, u16* __restrict__ vt)
{
  if (sniff_mode(xin) != F32) return;

  __shared__ __align__(16) u16 XnF[4 * 8 * 64 * 8];   // 32 KB (64 rows, A-frag order)
  __shared__ float lmr[64];
  const int tid = threadIdx.x;
  const int l = tid & 63, w = tid >> 6;
  const int lr = l & 15, quad = l >> 4;
  const int row0 = (blockIdx.x >> 1) * 64;
  const int nhalf = blockIdx.x & 1;

  // ---- Phase A: LayerNorm for 64 rows, frag-major store ----
  {
    const int r = tid >> 5, ln = tid & 31;
    float g[8], bb[8];
    load8<F32>(gamma, ln, g);
    load8<F32>(beta,  ln, bb);
    const int c = ln >> 2, qd = ln & 3;
#pragma unroll
    for (int p = 0; p < 8; ++p) {
      const int R = p * 8 + r;                 // local row 0..63
      const int grow = row0 + R;
      float x[8]; load8<F32>(xin, grow * 32 + ln, x);
      float s = 0.f, sq = 0.f;
#pragma unroll
      for (int j = 0; j < 8; ++j) { s += x[j]; sq += x[j] * x[j]; }
#pragma unroll
      for (int m = 1; m < 32; m <<= 1) { s += __shfl_xor(s, m); sq += __shfl_xor(sq, m); }
      const float mu  = s * (1.f / 256.f);
      const float var = sq * (1.f / 256.f) - mu * mu;
      const float rs  = rsqrtf(var + 1e-5f);
      short8 pk;
#pragma unroll
      for (int j = 0; j < 8; ++j) pk[j] = (short)f2b((x[j] - mu) * rs * g[j] + bb[j]);
      const int t = R >> 4, rm = R & 15;
      *(short8*)(XnF + (((t * 8 + c) * 64 + qd * 16 + rm) << 3)) = pk;
      if (ln == 0) lmr[R] = logf(load1<F32>(rmask, grow));
    }
  }
  __syncthreads();

  // ---- load A-fragments into registers (once) ----
  short8 Af[4][8];
#pragma unroll
  for (int mt = 0; mt < 4; ++mt)
#pragma unroll
    for (int c = 0; c < 8; ++c)
      Af[mt][c] = *(const short8*)(XnF + (((mt * 8 + c) * 64 + l) << 3));

  // ---- Phase B: 6 n-tiles/wave, constant-index B-frag dbuf ----
  const int bb_ = row0 >> 9;
  const int sB  = row0 & 511;
  const int tbase = nhalf * 24 + w * 6;

  short8 Bf[2][8];
#pragma unroll
  for (int c = 0; c < 8; ++c)
    Bf[0][c] = loadBfrag<F32>(wi, tbase * 16 + lr, c * 32 + quad * 8, 256);

#pragma unroll
  for (int nt = 0; nt < 6; ++nt) {
    const int cb = nt & 1;
    if (nt < 5) {
#pragma unroll
      for (int c = 0; c < 8; ++c)
        Bf[cb ^ 1][c] = loadBfrag<F32>(wi, (tbase + nt + 1) * 16 + lr, c * 32 + quad * 8, 256);
    }

    f32x4 a[4];
#pragma unroll
    for (int mt = 0; mt < 4; ++mt) a[mt] = (f32x4){0.f, 0.f, 0.f, 0.f};
#pragma unroll
    for (int c = 0; c < 8; ++c) {
#pragma unroll
      for (int mt = 0; mt < 4; ++mt)
        a[mt] = mfma16(Af[mt][c], Bf[cb][c], a[mt]);
    }

    const int nAbs  = (tbase + nt) * 16;
    const int type  = nAbs >> 8;              // 0=q 1=k 2=v
    const int dbase = nAbs & 255;
    if (type < 2) {
      const int d  = dbase + lr;
      const int h  = d >> 5, dd = d & 31;
      const int bh = bb_ * NH_ + h;
      u16* dst = (type == 0) ? qbuf : kbuf;
#pragma unroll
      for (int mt = 0; mt < 4; ++mt) {
        const int sL = mt * 16 + quad * 4;
#pragma unroll
        for (int i = 0; i < 4; ++i) {
          float v = a[mt][i];
          v = (type == 0) ? (v * v + 1e-6f) : (v + lmr[sL + i]);
          dst[((size_t)bh * S_ + sB + sL + i) * HD_ + dd] = f2b(v);
        }
      }
    } else {
      const int dv  = dbase + lr;             // v-dim 0..255
      const int hv  = dv >> 5, ddv = dv & 31;
      const int bhv = bb_ * NH_ + hv;
#pragma unroll
      for (int mt = 0; mt < 4; ++mt) {
        const int c16 = (sB >> 5) + (mt >> 1);
        const int slot16 = ((c16 * 2 + (ddv >> 4)) * 4 + quad) * 16 + (ddv & 15);
        uint2 pkv;
        pkv.x = pk2(a[mt][0], a[mt][1]);
        pkv.y = pk2(a[mt][2], a[mt][3]);
        *(uint2*)(vt + (size_t)bhv * (S_ * HD_) + slot16 * 8 + (mt & 1) * 4) = pkv;
      }
    }
  }
}

// ============================================================
// Kernel 2: LDS-free flash attention, online softmax in 4 chunks
// of 128 keys. Grid 2048 = (sq)*256 + bh (XCD swizzle).
// V sigma-key-permuted. (unchanged from R8)
// ============================================================
__global__ __launch_bounds__(256, 4) void attn_mfma(
    const u16* __restrict__ qbuf, const u16* __restrict__ kbuf,
    const u16* __restrict__ vt, u16* __restrict__ ctx)
{
  __shared__ __align__(16) u16 OB[4][16 * 40];   // wave-private out transpose (5 KB)
  const int tid = threadIdx.x;
  const int bh = blockIdx.x & 255, sq = blockIdx.x >> 8;
  const int l = tid & 63, w = tid >> 6;
  const int lr = l & 15, quad = l >> 4;
  const size_t kvbase = (size_t)bh * (S_ * HD_);
  const int q0 = sq * 64 + w * 16;

  const float cE = 0.17677669529663688f * 1.4426950408889634f; // (1/sqrt(32))*log2(e)

  const short8 qf = *(const short8*)(qbuf + kvbase + (size_t)(q0 + lr) * HD_ + quad * 8);
  const u16* kp = kbuf + kvbase + (size_t)lr * HD_ + quad * 8;
  const u16* vp = vt + kvbase;

  float mS = -1e30f, lS = 0.f;
  f32x4 o0 = {0.f,0.f,0.f,0.f}, o1 = {0.f,0.f,0.f,0.f};

#pragma unroll
  for (int c = 0; c < 4; ++c) {
    f32x4 acc[8];
#pragma unroll
    for (int j = 0; j < 8; ++j) {
      const short8 kf = *(const short8*)(kp + (c * 8 + j) * (16 * HD_));
      f32x4 z = {0.f,0.f,0.f,0.f};
      acc[j] = mfma16(kf, qf, z);
    }

    float mc = acc[0][0];
#pragma unroll
    for (int j = 0; j < 8; ++j)
#pragma unroll
      for (int r = 0; r < 4; ++r) mc = fmaxf(mc, acc[j][r]);
    mc = fmaxf(mc, __shfl_xor(mc, 16));
    mc = fmaxf(mc, __shfl_xor(mc, 32));
    const float mNew  = fmaxf(mS, mc * cE);
    const float alpha = exp2f(mS - mNew);
    float sc = 0.f;
#pragma unroll
    for (int j = 0; j < 8; ++j)
#pragma unroll
      for (int r = 0; r < 4; ++r) {
        const float p = exp2f(fmaf(acc[j][r], cE, -mNew));
        acc[j][r] = p; sc += p;
      }
    sc += __shfl_xor(sc, 16);
    sc += __shfl_xor(sc, 32);
    lS = fmaf(lS, alpha, sc);
    mS = mNew;
#pragma unroll
    for (int r = 0; r < 4; ++r) { o0[r] *= alpha; o1[r] *= alpha; }

#pragma unroll
    for (int g = 0; g < 4; ++g) {
      union { u32 u[4]; short8 s; } pa;
      pa.u[0] = pk2(acc[2*g][0],   acc[2*g][1]);
      pa.u[1] = pk2(acc[2*g][2],   acc[2*g][3]);
      pa.u[2] = pk2(acc[2*g+1][0], acc[2*g+1][1]);
      pa.u[3] = pk2(acc[2*g+1][2], acc[2*g+1][3]);
      const int c16 = c * 4 + g;
      const short8 v0 = *(const short8*)(vp + (((c16 * 8 +     quad) * 16 + lr) << 3));
      const short8 v1 = *(const short8*)(vp + (((c16 * 8 + 4 + quad) * 16 + lr) << 3));
      o0 = mfma16(pa.s, v0, o0);
      o1 = mfma16(pa.s, v1, o1);
    }
  }
  const float inv = 1.f / lS;

  u16* ob = OB[w];
#pragma unroll
  for (int r = 0; r < 4; ++r) {
    const int qq = quad * 4 + r;
    const float iv = __shfl(inv, (l & 48) | qq);
    ob[qq * 40 + lr]      = f2b(o0[r] * iv);
    ob[qq * 40 + 16 + lr] = f2b(o1[r] * iv);
  }
  const uint4 ov = *(const uint4*)(ob + (l >> 2) * 40 + (l & 3) * 8);
  *(uint4*)(ctx + kvbase + (size_t)(q0 + (l >> 2)) * HD_ + (l & 3) * 8) = ov;
}

// ============================================================
// Kernel 3: out-proj via MFMA + residual + sqrt(1/2).
// Grid 1024 (M=16). A-frags register-resident, constant-index dbuf.
// ============================================================
template<int F32>
__global__ __launch_bounds__(256) void proj_mfma(
    const u16* __restrict__ ctx, const void* __restrict__ xin,
    const void* __restrict__ wo, void* __restrict__ out)
{
  if (sniff_mode(xin) != F32) return;

  __shared__ __align__(16) u16 XnF[8 * 64 * 8];   // 8 KB (one m-tile)
  __shared__ __align__(16) u16 OutB[16 * 264];    // 8.25 KB
  const int tid = threadIdx.x;
  const int l = tid & 63, w = tid >> 6;
  const int lr = l & 15, quad = l >> 4;
  const int row0 = blockIdx.x * 16;
  const int b = row0 >> 9, s0 = row0 & 511;

  // ---- stage ctx -> A-frag LDS (swizzled) ----
#pragma unroll
  for (int it = 0; it < 2; ++it) {
    const int idx = it * 256 + tid;          // 0..511 : 16 rows x 32 uint4
    const int dq = idx & 3, sl = (idx >> 2) & 15, h = idx >> 6;
    const uint4 cv = *(const uint4*)(ctx + ((size_t)(b * 8 + h) * S_ + s0 + sl) * HD_ + dq * 8);
    const int qds = dq ^ (sl & 3);
    *(uint4*)(XnF + ((h * 64 + qds * 16 + sl) << 3)) = cv;
  }
  __syncthreads();

  const int lsw = (quad ^ (lr & 3)) * 16 + lr;
  short8 Af[8];
#pragma unroll
  for (int c = 0; c < 8; ++c)
    Af[c] = *(const short8*)(XnF + ((c * 64 + lsw) << 3));

  short8 Bf[2][8];
#pragma unroll
  for (int c = 0; c < 8; ++c)
    Bf[0][c] = loadBfrag<F32>(wo, (w * 4) * 16 + lr, c * 32 + quad * 8, 256);

#pragma unroll
  for (int nt = 0; nt < 4; ++nt) {
    const int cb = nt & 1;
    if (nt < 3) {
#pragma unroll
      for (int c = 0; c < 8; ++c)
        Bf[cb ^ 1][c] = loadBfrag<F32>(wo, (w * 4 + nt + 1) * 16 + lr, c * 32 + quad * 8, 256);
    }
    const int n0 = (w * 4 + nt) * 16;
    f32x4 a0 = {0.f,0.f,0.f,0.f};
#pragma unroll
    for (int c = 0; c < 8; ++c)
      a0 = mfma16(Af[c], Bf[cb][c], a0);
#pragma unroll
    for (int i = 0; i < 4; ++i)
      OutB[(quad * 4 + i) * 264 + n0 + lr] = f2b(a0[i]);
  }
  __syncthreads();

  // ---- epilogue: residual + scale, vectorized coalesced store ----
  const int r  = tid >> 4;             // 0..15
  const int c8 = (tid & 15) * 2;       // e8 base within row
#pragma unroll
  for (int j8 = 0; j8 < 2; ++j8) {
    float xv[8]; load8<F32>(xin, (row0 + r) * 32 + c8 + j8, xv);
    float pv[8]; unp8(*(const uint4*)(OutB + r * 264 + (c8 + j8) * 8), pv);
    float ov[8];
#pragma unroll
    for (int j = 0; j < 8; ++j) ov[j] = (pv[j] + xv[j]) * 0.70710678f;
    store8<F32>(out, (row0 + r) * 32 + c8 + j8, ov);
  }
}

// ============================================================
extern "C" void kernel_launch(void* const* d_in, const int* in_sizes, int n_in,
                              void* d_out, int out_size, void* d_ws, size_t ws_size,
                              hipStream_t stream)
{
  const void* xin   = d_in[0];
  const void* rmask = d_in[1];
  const void* wi    = d_in[2];
  const void* wo    = d_in[3];
  const void* gam   = d_in[4];
  const void* bet   = d_in[5];

  u16* q   = (u16*)d_ws;                   // [256][512][32] bf16 (8 MB)
  u16* k   = q + 4194304;
  u16* vt  = k + 4194304;                  // sigma-permuted V (8 MB)
  u16* cxb = vt + 4194304;                 // ctx [bh][s][hd] bf16 (8 MB)

  ln_qkv_mfma<0><<<512,  256, 0, stream>>>(xin, rmask, wi, gam, bet, q, k, vt);
  ln_qkv_mfma<1><<<512,  256, 0, stream>>>(xin, rmask, wi, gam, bet, q, k, vt);
  attn_mfma     <<<2048, 256, 0, stream>>>(q, k, vt, cxb);
  proj_mfma<0>  <<<1024, 256, 0, stream>>>(cxb, xin, wo, d_out);
  proj_mfma<1>  <<<1024, 256, 0, stream>>>(cxb, xin, wo, d_out);
}

// Round 10
// 167.825 us; speedup vs baseline: 1.4445x; 1.0787x over previous
//
#include <hip/hip_runtime.h>
#include <hip/hip_bf16.h>

typedef unsigned int u32;
typedef unsigned short u16;

#define B_   32
#define S_   512
#define H_   256
#define NH_  8
#define HD_  32

typedef __attribute__((ext_vector_type(8))) short short8;
typedef __attribute__((ext_vector_type(4))) float f32x4;

// ---------- bf16 helpers ----------
__device__ __forceinline__ float bfl(u32 u){ union{u32 i;float f;} c; c.i = u << 16;          return c.f; }
__device__ __forceinline__ float bfh(u32 u){ union{u32 i;float f;} c; c.i = u & 0xffff0000u;  return c.f; }
__device__ __forceinline__ float bf1(u16 u){ union{u32 i;float f;} c; c.i = ((u32)u) << 16;   return c.f; }
__device__ __forceinline__ u16   f2b(float f){ __hip_bfloat16 h = __float2bfloat16(f); return *reinterpret_cast<u16*>(&h); }
__device__ __forceinline__ u32   pk2(float a, float b){ return (u32)f2b(a) | ((u32)f2b(b) << 16); }
__device__ __forceinline__ void  unp8(const uint4 u, float* f){
  f[0]=bfl(u.x); f[1]=bfh(u.x); f[2]=bfl(u.y); f[3]=bfh(u.y);
  f[4]=bfl(u.z); f[5]=bfh(u.z); f[6]=bfl(u.w); f[7]=bfh(u.w);
}
__device__ __forceinline__ f32x4 mfma16(short8 a, short8 b, f32x4 c){
  return __builtin_amdgcn_mfma_f32_16x16x32_bf16(a, b, c, 0, 0, 0);
}

// ---------- dtype-polymorphic loads/stores ----------
template<int F32>
__device__ __forceinline__ void load8(const void* p, int e8, float* f) {
  if (F32) {
    const float4* q = (const float4*)p;
    const float4 a = q[e8 * 2], b = q[e8 * 2 + 1];
    f[0]=a.x; f[1]=a.y; f[2]=a.z; f[3]=a.w; f[4]=b.x; f[5]=b.y; f[6]=b.z; f[7]=b.w;
  } else {
    unp8(((const uint4*)p)[e8], f);
  }
}
template<int F32>
__device__ __forceinline__ void store8(void* p, int e8, const float* f) {
  if (F32) {
    float4* q = (float4*)p;
    q[e8 * 2]     = make_float4(f[0], f[1], f[2], f[3]);
    q[e8 * 2 + 1] = make_float4(f[4], f[5], f[6], f[7]);
  } else {
    uint4 u;
    u.x = pk2(f[0], f[1]); u.y = pk2(f[2], f[3]);
    u.z = pk2(f[4], f[5]); u.w = pk2(f[6], f[7]);
    ((uint4*)p)[e8] = u;
  }
}
template<int F32>
__device__ __forceinline__ float load1(const void* p, size_t e) {
  return F32 ? ((const float*)p)[e] : bf1(((const u16*)p)[e]);
}
template<int F32>
__device__ __forceinline__ short8 loadBfrag(const void* wp, int row, int k0, int K) {
  if (F32) {
    const float* w = (const float*)wp + (size_t)row * K + k0;
    const float4 a = *(const float4*)w;
    const float4 b = *(const float4*)(w + 4);
    short8 r;
    r[0]=(short)f2b(a.x); r[1]=(short)f2b(a.y); r[2]=(short)f2b(a.z); r[3]=(short)f2b(a.w);
    r[4]=(short)f2b(b.x); r[5]=(short)f2b(b.y); r[6]=(short)f2b(b.z); r[7]=(short)f2b(b.w);
    return r;
  } else {
    return *(const short8*)((const u16*)wp + (size_t)row * K + k0);
  }
}

// ---------- dtype sniff (first 4KB of `inputs`), one atomic per wave ----------
__device__ __forceinline__ int sniff_mode(const void* xin) {   // 0=bf16, 1=f32
  __shared__ int votes;
  const int tid = threadIdx.x;
  if (tid == 0) votes = 0;
  __syncthreads();
  const u32* xw = (const u32*)xin;
  int h = 0;
#pragma unroll
  for (int j = 0; j < 4; ++j) {
    const u32 u = xw[(tid << 2) + j];
    const u32 e = (u >> 7) & 0xFF;
    h += (e >= 100 && e <= 135) ? 1 : 0;
  }
  const unsigned long long m = __ballot(h >= 3);
  if ((tid & 63) == 0) atomicAdd(&votes, __popcll(m));
  __syncthreads();
  return (votes >= 128) ? 0 : 1;
}

// ============================================================
// Kernel 1: LN + QKV via MFMA (unchanged from R9).
// Grid 512 = (m-superblock 64 rows) x nhalf. A-frags register-resident.
// ============================================================
template<int F32>
__global__ __launch_bounds__(256, 2) void ln_qkv_mfma(
    const void* __restrict__ xin, const void* __restrict__ rmask,
    const void* __restrict__ wi, const void* __restrict__ gamma,
    const void* __restrict__ beta,
    u16* __restrict__ qbuf, u16* __restrict__ kbuf, u16* __restrict__ vt)
{
  if (sniff_mode(xin) != F32) return;

  __shared__ __align__(16) u16 XnF[4 * 8 * 64 * 8];   // 32 KB
  __shared__ float lmr[64];
  const int tid = threadIdx.x;
  const int l = tid & 63, w = tid >> 6;
  const int lr = l & 15, quad = l >> 4;
  const int row0 = (blockIdx.x >> 1) * 64;
  const int nhalf = blockIdx.x & 1;

  {
    const int r = tid >> 5, ln = tid & 31;
    float g[8], bb[8];
    load8<F32>(gamma, ln, g);
    load8<F32>(beta,  ln, bb);
    const int c = ln >> 2, qd = ln & 3;
#pragma unroll
    for (int p = 0; p < 8; ++p) {
      const int R = p * 8 + r;
      const int grow = row0 + R;
      float x[8]; load8<F32>(xin, grow * 32 + ln, x);
      float s = 0.f, sq = 0.f;
#pragma unroll
      for (int j = 0; j < 8; ++j) { s += x[j]; sq += x[j] * x[j]; }
#pragma unroll
      for (int m = 1; m < 32; m <<= 1) { s += __shfl_xor(s, m); sq += __shfl_xor(sq, m); }
      const float mu  = s * (1.f / 256.f);
      const float var = sq * (1.f / 256.f) - mu * mu;
      const float rs  = rsqrtf(var + 1e-5f);
      short8 pk;
#pragma unroll
      for (int j = 0; j < 8; ++j) pk[j] = (short)f2b((x[j] - mu) * rs * g[j] + bb[j]);
      const int t = R >> 4, rm = R & 15;
      *(short8*)(XnF + (((t * 8 + c) * 64 + qd * 16 + rm) << 3)) = pk;
      if (ln == 0) lmr[R] = logf(load1<F32>(rmask, grow));
    }
  }
  __syncthreads();

  short8 Af[4][8];
#pragma unroll
  for (int mt = 0; mt < 4; ++mt)
#pragma unroll
    for (int c = 0; c < 8; ++c)
      Af[mt][c] = *(const short8*)(XnF + (((mt * 8 + c) * 64 + l) << 3));

  const int bb_ = row0 >> 9;
  const int sB  = row0 & 511;
  const int tbase = nhalf * 24 + w * 6;

  short8 Bf[2][8];
#pragma unroll
  for (int c = 0; c < 8; ++c)
    Bf[0][c] = loadBfrag<F32>(wi, tbase * 16 + lr, c * 32 + quad * 8, 256);

#pragma unroll
  for (int nt = 0; nt < 6; ++nt) {
    const int cb = nt & 1;
    if (nt < 5) {
#pragma unroll
      for (int c = 0; c < 8; ++c)
        Bf[cb ^ 1][c] = loadBfrag<F32>(wi, (tbase + nt + 1) * 16 + lr, c * 32 + quad * 8, 256);
    }

    f32x4 a[4];
#pragma unroll
    for (int mt = 0; mt < 4; ++mt) a[mt] = (f32x4){0.f, 0.f, 0.f, 0.f};
#pragma unroll
    for (int c = 0; c < 8; ++c) {
#pragma unroll
      for (int mt = 0; mt < 4; ++mt)
        a[mt] = mfma16(Af[mt][c], Bf[cb][c], a[mt]);
    }

    const int nAbs  = (tbase + nt) * 16;
    const int type  = nAbs >> 8;
    const int dbase = nAbs & 255;
    if (type < 2) {
      const int d  = dbase + lr;
      const int h  = d >> 5, dd = d & 31;
      const int bh = bb_ * NH_ + h;
      u16* dst = (type == 0) ? qbuf : kbuf;
#pragma unroll
      for (int mt = 0; mt < 4; ++mt) {
        const int sL = mt * 16 + quad * 4;
#pragma unroll
        for (int i = 0; i < 4; ++i) {
          float v = a[mt][i];
          v = (type == 0) ? (v * v + 1e-6f) : (v + lmr[sL + i]);
          dst[((size_t)bh * S_ + sB + sL + i) * HD_ + dd] = f2b(v);
        }
      }
    } else {
      const int dv  = dbase + lr;
      const int hv  = dv >> 5, ddv = dv & 31;
      const int bhv = bb_ * NH_ + hv;
#pragma unroll
      for (int mt = 0; mt < 4; ++mt) {
        const int c16 = (sB >> 5) + (mt >> 1);
        const int slot16 = ((c16 * 2 + (ddv >> 4)) * 4 + quad) * 16 + (ddv & 15);
        uint2 pkv;
        pkv.x = pk2(a[mt][0], a[mt][1]);
        pkv.y = pk2(a[mt][2], a[mt][3]);
        *(uint2*)(vt + (size_t)bhv * (S_ * HD_) + slot16 * 8 + (mt & 1) * 4) = pkv;
      }
    }
  }
}

// ============================================================
// Kernel 2: LDS-free flash attention, online softmax, 2 q-tiles/wave
// (32 queries). Grid 1024 = (sq 0..3)*256 + bh (XCD swizzle).
// Each K-frag / V-frag load feeds 2 MFMAs. V sigma-key-permuted.
// ============================================================
__global__ __launch_bounds__(256, 3) void attn_mfma(
    const u16* __restrict__ qbuf, const u16* __restrict__ kbuf,
    const u16* __restrict__ vt, u16* __restrict__ ctx)
{
  __shared__ __align__(16) u16 OB[4][32 * 40];   // wave-private out transpose (10 KB)
  const int tid = threadIdx.x;
  const int bh = blockIdx.x & 255, sq = blockIdx.x >> 8;
  const int l = tid & 63, w = tid >> 6;
  const int lr = l & 15, quad = l >> 4;
  const size_t kvbase = (size_t)bh * (S_ * HD_);
  const int q0 = sq * 128 + w * 32;              // 32 queries per wave

  const float cE = 0.17677669529663688f * 1.4426950408889634f; // (1/sqrt(32))*log2(e)

  const short8 qfA = *(const short8*)(qbuf + kvbase + (size_t)(q0 + lr) * HD_ + quad * 8);
  const short8 qfB = *(const short8*)(qbuf + kvbase + (size_t)(q0 + 16 + lr) * HD_ + quad * 8);
  const u16* kp = kbuf + kvbase + (size_t)lr * HD_ + quad * 8;
  const u16* vp = vt + kvbase;

  float mSA = -1e30f, lSA = 0.f, mSB = -1e30f, lSB = 0.f;
  f32x4 oA0 = {0.f,0.f,0.f,0.f}, oA1 = {0.f,0.f,0.f,0.f};
  f32x4 oB0 = {0.f,0.f,0.f,0.f}, oB1 = {0.f,0.f,0.f,0.f};

#pragma unroll
  for (int c = 0; c < 4; ++c) {
    // ---- QK^T chunk: keys c*128 .. +127, both q-tiles per K-load ----
    f32x4 aA[8], aB[8];
#pragma unroll
    for (int j = 0; j < 8; ++j) {
      const short8 kf = *(const short8*)(kp + (c * 8 + j) * (16 * HD_));
      f32x4 z = {0.f,0.f,0.f,0.f};
      aA[j] = mfma16(kf, qfA, z);
      aB[j] = mfma16(kf, qfB, z);
    }

    // ---- online softmax updates ----
    float mcA = aA[0][0], mcB = aB[0][0];
#pragma unroll
    for (int j = 0; j < 8; ++j)
#pragma unroll
      for (int r = 0; r < 4; ++r) { mcA = fmaxf(mcA, aA[j][r]); mcB = fmaxf(mcB, aB[j][r]); }
    mcA = fmaxf(mcA, __shfl_xor(mcA, 16)); mcB = fmaxf(mcB, __shfl_xor(mcB, 16));
    mcA = fmaxf(mcA, __shfl_xor(mcA, 32)); mcB = fmaxf(mcB, __shfl_xor(mcB, 32));
    const float mNA = fmaxf(mSA, mcA * cE), mNB = fmaxf(mSB, mcB * cE);
    const float alA = exp2f(mSA - mNA),     alB = exp2f(mSB - mNB);
    float scA = 0.f, scB = 0.f;
#pragma unroll
    for (int j = 0; j < 8; ++j)
#pragma unroll
      for (int r = 0; r < 4; ++r) {
        const float pA = exp2f(fmaf(aA[j][r], cE, -mNA));
        const float pB = exp2f(fmaf(aB[j][r], cE, -mNB));
        aA[j][r] = pA; scA += pA;
        aB[j][r] = pB; scB += pB;
      }
    scA += __shfl_xor(scA, 16); scB += __shfl_xor(scB, 16);
    scA += __shfl_xor(scA, 32); scB += __shfl_xor(scB, 32);
    lSA = fmaf(lSA, alA, scA); mSA = mNA;
    lSB = fmaf(lSB, alB, scB); mSB = mNB;
#pragma unroll
    for (int r = 0; r < 4; ++r) {
      oA0[r] *= alA; oA1[r] *= alA;
      oB0[r] *= alB; oB1[r] *= alB;
    }

    // ---- PV chunk: each V-load feeds both q-tiles ----
#pragma unroll
    for (int g = 0; g < 4; ++g) {
      const int c16 = c * 4 + g;
      const short8 v0 = *(const short8*)(vp + (((c16 * 8 +     quad) * 16 + lr) << 3));
      const short8 v1 = *(const short8*)(vp + (((c16 * 8 + 4 + quad) * 16 + lr) << 3));
      union { u32 u[4]; short8 s; } pa;
      pa.u[0] = pk2(aA[2*g][0],   aA[2*g][1]);
      pa.u[1] = pk2(aA[2*g][2],   aA[2*g][3]);
      pa.u[2] = pk2(aA[2*g+1][0], aA[2*g+1][1]);
      pa.u[3] = pk2(aA[2*g+1][2], aA[2*g+1][3]);
      oA0 = mfma16(pa.s, v0, oA0);
      oA1 = mfma16(pa.s, v1, oA1);
      pa.u[0] = pk2(aB[2*g][0],   aB[2*g][1]);
      pa.u[1] = pk2(aB[2*g][2],   aB[2*g][3]);
      pa.u[2] = pk2(aB[2*g+1][0], aB[2*g+1][1]);
      pa.u[3] = pk2(aB[2*g+1][2], aB[2*g+1][3]);
      oB0 = mfma16(pa.s, v0, oB0);
      oB1 = mfma16(pa.s, v1, oB1);
    }
  }
  const float invA = 1.f / lSA, invB = 1.f / lSB;

  // ---- epilogue: wave-private LDS transpose, coalesced 16B stores ----
  u16* ob = OB[w];
#pragma unroll
  for (int r = 0; r < 4; ++r) {
    const int qq = quad * 4 + r;
    const float ivA = __shfl(invA, (l & 48) | qq);
    const float ivB = __shfl(invB, (l & 48) | qq);
    ob[qq * 40 + lr]             = f2b(oA0[r] * ivA);
    ob[qq * 40 + 16 + lr]        = f2b(oA1[r] * ivA);
    ob[(16 + qq) * 40 + lr]      = f2b(oB0[r] * ivB);
    ob[(16 + qq) * 40 + 16 + lr] = f2b(oB1[r] * ivB);
  }
#pragma unroll
  for (int t = 0; t < 2; ++t) {
    const int row = (l >> 2) + t * 16;
    const uint4 ov = *(const uint4*)(ob + row * 40 + (l & 3) * 8);
    *(uint4*)(ctx + kvbase + (size_t)(q0 + row) * HD_ + (l & 3) * 8) = ov;
  }
}

// ============================================================
// Kernel 3: out-proj via MFMA + residual + sqrt(1/2).
// Grid 512 (M=32): 2 m-tiles register-resident, constant-index dbuf.
// ============================================================
template<int F32>
__global__ __launch_bounds__(256, 2) void proj_mfma(
    const u16* __restrict__ ctx, const void* __restrict__ xin,
    const void* __restrict__ wo, void* __restrict__ out)
{
  if (sniff_mode(xin) != F32) return;

  __shared__ __align__(16) u16 XnF[2 * 8 * 64 * 8];   // 16 KB
  __shared__ __align__(16) u16 OutB[32 * 264];        // 16.5 KB
  const int tid = threadIdx.x;
  const int l = tid & 63, w = tid >> 6;
  const int lr = l & 15, quad = l >> 4;
  const int row0 = blockIdx.x * 32;
  const int b = row0 >> 9, s0 = row0 & 511;

  // ---- stage ctx -> A-frag LDS (swizzled) ----
#pragma unroll
  for (int it = 0; it < 4; ++it) {
    const int idx = it * 256 + tid;          // 0..1023 : 32 rows x 8 heads x 4 dq
    const int dq = idx & 3, sl = (idx >> 2) & 31, h = idx >> 7;
    const uint4 cv = *(const uint4*)(ctx + ((size_t)(b * 8 + h) * S_ + s0 + sl) * HD_ + dq * 8);
    const int t = sl >> 4, rm = sl & 15;
    const int qds = dq ^ (rm & 3);
    *(uint4*)(XnF + (((t * 8 + h) * 64 + qds * 16 + rm) << 3)) = cv;
  }
  __syncthreads();

  const int lsw = (quad ^ (lr & 3)) * 16 + lr;
  short8 Af[2][8];
#pragma unroll
  for (int mt = 0; mt < 2; ++mt)
#pragma unroll
    for (int c = 0; c < 8; ++c)
      Af[mt][c] = *(const short8*)(XnF + (((mt * 8 + c) * 64 + lsw) << 3));

  short8 Bf[2][8];
#pragma unroll
  for (int c = 0; c < 8; ++c)
    Bf[0][c] = loadBfrag<F32>(wo, (w * 4) * 16 + lr, c * 32 + quad * 8, 256);

#pragma unroll
  for (int nt = 0; nt < 4; ++nt) {
    const int cb = nt & 1;
    if (nt < 3) {
#pragma unroll
      for (int c = 0; c < 8; ++c)
        Bf[cb ^ 1][c] = loadBfrag<F32>(wo, (w * 4 + nt + 1) * 16 + lr, c * 32 + quad * 8, 256);
    }
    const int n0 = (w * 4 + nt) * 16;
    f32x4 a0 = {0.f,0.f,0.f,0.f}, a1 = {0.f,0.f,0.f,0.f};
#pragma unroll
    for (int c = 0; c < 8; ++c) {
      a0 = mfma16(Af[0][c], Bf[cb][c], a0);
      a1 = mfma16(Af[1][c], Bf[cb][c], a1);
    }
#pragma unroll
    for (int m = 0; m < 2; ++m) {
      const f32x4 acc = m ? a1 : a0;
#pragma unroll
      for (int i = 0; i < 4; ++i)
        OutB[(m * 16 + quad * 4 + i) * 264 + n0 + lr] = f2b(acc[i]);
    }
  }
  __syncthreads();

  // ---- epilogue: residual + scale, vectorized coalesced store ----
  const int r  = tid >> 3;             // 0..31
  const int c8 = (tid & 7) * 4;
#pragma unroll
  for (int j8 = 0; j8 < 4; ++j8) {
    float xv[8]; load8<F32>(xin, (row0 + r) * 32 + c8 + j8, xv);
    float pv[8]; unp8(*(const uint4*)(OutB + r * 264 + (c8 + j8) * 8), pv);
    float ov[8];
#pragma unroll
    for (int j = 0; j < 8; ++j) ov[j] = (pv[j] + xv[j]) * 0.70710678f;
    store8<F32>(out, (row0 + r) * 32 + c8 + j8, ov);
  }
}

// ============================================================
extern "C" void kernel_launch(void* const* d_in, const int* in_sizes, int n_in,
                              void* d_out, int out_size, void* d_ws, size_t ws_size,
                              hipStream_t stream)
{
  const void* xin   = d_in[0];
  const void* rmask = d_in[1];
  const void* wi    = d_in[2];
  const void* wo    = d_in[3];
  const void* gam   = d_in[4];
  const void* bet   = d_in[5];

  u16* q   = (u16*)d_ws;                   // [256][512][32] bf16 (8 MB)
  u16* k   = q + 4194304;
  u16* vt  = k + 4194304;                  // sigma-permuted V (8 MB)
  u16* cxb = vt + 4194304;                 // ctx [bh][s][hd] bf16 (8 MB)

  ln_qkv_mfma<0><<<512,  256, 0, stream>>>(xin, rmask, wi, gam, bet, q, k, vt);
  ln_qkv_mfma<1><<<512,  256, 0, stream>>>(xin, rmask, wi, gam, bet, q, k, vt);
  attn_mfma     <<<1024, 256, 0, stream>>>(q, k, vt, cxb);
  proj_mfma<0>  <<<512,  256, 0, stream>>>(cxb, xin, wo, d_out);
  proj_mfma<1>  <<<512,  256, 0, stream>>>(cxb, xin, wo, d_out);
}

// Round 11
// 166.760 us; speedup vs baseline: 1.4537x; 1.0064x over previous
//
#include <hip/hip_runtime.h>
#include <hip/hip_bf16.h>

typedef unsigned int u32;
typedef unsigned short u16;

#define B_   32
#define S_   512
#define H_   256
#define NH_  8
#define HD_  32

typedef __attribute__((ext_vector_type(8))) short short8;
typedef __attribute__((ext_vector_type(4))) float f32x4;

// ---------- bf16 helpers (fast RNE, finite inputs only) ----------
__device__ __forceinline__ u32   fbits(float f){ union{float f;u32 u;} c; c.f=f; return c.u; }
__device__ __forceinline__ float bfl(u32 u){ union{u32 i;float f;} c; c.i = u << 16;          return c.f; }
__device__ __forceinline__ float bfh(u32 u){ union{u32 i;float f;} c; c.i = u & 0xffff0000u;  return c.f; }
__device__ __forceinline__ float bf1(u16 u){ union{u32 i;float f;} c; c.i = ((u32)u) << 16;   return c.f; }
__device__ __forceinline__ u16   f2b(float f){ const u32 u = fbits(f); return (u16)((u + 0x7fffu + ((u >> 16) & 1u)) >> 16); }
__device__ __forceinline__ u32   pk2(float a, float b){
  const u32 ua = fbits(a), ub = fbits(b);
  const u32 ra = (ua + 0x7fffu + ((ua >> 16) & 1u)) >> 16;
  const u32 rb = (ub + 0x7fffu + ((ub >> 16) & 1u)) & 0xffff0000u;
  return ra | rb;
}
__device__ __forceinline__ void  unp8(const uint4 u, float* f){
  f[0]=bfl(u.x); f[1]=bfh(u.x); f[2]=bfl(u.y); f[3]=bfh(u.y);
  f[4]=bfl(u.z); f[5]=bfh(u.z); f[6]=bfl(u.w); f[7]=bfh(u.w);
}
__device__ __forceinline__ f32x4 mfma16(short8 a, short8 b, f32x4 c){
  return __builtin_amdgcn_mfma_f32_16x16x32_bf16(a, b, c, 0, 0, 0);
}

// ---------- dtype-polymorphic loads/stores ----------
template<int F32>
__device__ __forceinline__ void load8(const void* p, int e8, float* f) {
  if (F32) {
    const float4* q = (const float4*)p;
    const float4 a = q[e8 * 2], b = q[e8 * 2 + 1];
    f[0]=a.x; f[1]=a.y; f[2]=a.z; f[3]=a.w; f[4]=b.x; f[5]=b.y; f[6]=b.z; f[7]=b.w;
  } else {
    unp8(((const uint4*)p)[e8], f);
  }
}
template<int F32>
__device__ __forceinline__ void store8(void* p, int e8, const float* f) {
  if (F32) {
    float4* q = (float4*)p;
    q[e8 * 2]     = make_float4(f[0], f[1], f[2], f[3]);
    q[e8 * 2 + 1] = make_float4(f[4], f[5], f[6], f[7]);
  } else {
    uint4 u;
    u.x = pk2(f[0], f[1]); u.y = pk2(f[2], f[3]);
    u.z = pk2(f[4], f[5]); u.w = pk2(f[6], f[7]);
    ((uint4*)p)[e8] = u;
  }
}
template<int F32>
__device__ __forceinline__ float load1(const void* p, size_t e) {
  return F32 ? ((const float*)p)[e] : bf1(((const u16*)p)[e]);
}
template<int F32>
__device__ __forceinline__ short8 loadBfrag(const void* wp, int row, int k0, int K) {
  if (F32) {
    const float* w = (const float*)wp + (size_t)row * K + k0;
    const float4 a = *(const float4*)w;
    const float4 b = *(const float4*)(w + 4);
    union { u32 u[4]; short8 s; } r;
    r.u[0] = pk2(a.x, a.y); r.u[1] = pk2(a.z, a.w);
    r.u[2] = pk2(b.x, b.y); r.u[3] = pk2(b.z, b.w);
    return r.s;
  } else {
    return *(const short8*)((const u16*)wp + (size_t)row * K + k0);
  }
}

// ---------- dtype sniff (first 4KB of `inputs`), one atomic per wave ----------
__device__ __forceinline__ int sniff_mode(const void* xin) {   // 0=bf16, 1=f32
  __shared__ int votes;
  const int tid = threadIdx.x;
  if (tid == 0) votes = 0;
  __syncthreads();
  const u32* xw = (const u32*)xin;
  int h = 0;
#pragma unroll
  for (int j = 0; j < 4; ++j) {
    const u32 u = xw[(tid << 2) + j];
    const u32 e = (u >> 7) & 0xFF;
    h += (e >= 100 && e <= 135) ? 1 : 0;
  }
  const unsigned long long m = __ballot(h >= 3);
  if ((tid & 63) == 0) atomicAdd(&votes, __popcll(m));
  __syncthreads();
  return (votes >= 128) ? 0 : 1;
}

// ============================================================
// LN + QKV body (R9/R10-proven structure).
// ============================================================
template<int F32>
__device__ __forceinline__ void ln_body(
    const void* __restrict__ xin, const void* __restrict__ rmask,
    const void* __restrict__ wi, const void* __restrict__ gamma,
    const void* __restrict__ beta,
    u16* __restrict__ qbuf, u16* __restrict__ kbuf, u16* __restrict__ vt,
    u16* XnF, float* lmr)
{
  const int tid = threadIdx.x;
  const int l = tid & 63, w = tid >> 6;
  const int lr = l & 15, quad = l >> 4;
  const int row0 = (blockIdx.x >> 1) * 64;
  const int nhalf = blockIdx.x & 1;

  {
    const int r = tid >> 5, ln = tid & 31;
    float g[8], bb[8];
    load8<F32>(gamma, ln, g);
    load8<F32>(beta,  ln, bb);
    const int c = ln >> 2, qd = ln & 3;
#pragma unroll
    for (int p = 0; p < 8; ++p) {
      const int R = p * 8 + r;
      const int grow = row0 + R;
      float x[8]; load8<F32>(xin, grow * 32 + ln, x);
      float s = 0.f, sq = 0.f;
#pragma unroll
      for (int j = 0; j < 8; ++j) { s += x[j]; sq += x[j] * x[j]; }
#pragma unroll
      for (int m = 1; m < 32; m <<= 1) { s += __shfl_xor(s, m); sq += __shfl_xor(sq, m); }
      const float mu  = s * (1.f / 256.f);
      const float var = sq * (1.f / 256.f) - mu * mu;
      const float rs  = rsqrtf(var + 1e-5f);
      union { u32 u[4]; short8 s8; } pk;
#pragma unroll
      for (int j = 0; j < 4; ++j)
        pk.u[j] = pk2((x[2*j] - mu) * rs * g[2*j] + bb[2*j],
                      (x[2*j+1] - mu) * rs * g[2*j+1] + bb[2*j+1]);
      const int t = R >> 4, rm = R & 15;
      *(short8*)(XnF + (((t * 8 + c) * 64 + qd * 16 + rm) << 3)) = pk.s8;
      if (ln == 0) lmr[R] = logf(load1<F32>(rmask, grow));
    }
  }
  __syncthreads();

  short8 Af[4][8];
#pragma unroll
  for (int mt = 0; mt < 4; ++mt)
#pragma unroll
    for (int c = 0; c < 8; ++c)
      Af[mt][c] = *(const short8*)(XnF + (((mt * 8 + c) * 64 + l) << 3));

  const int bb_ = row0 >> 9;
  const int sB  = row0 & 511;
  const int tbase = nhalf * 24 + w * 6;

  short8 Bf[2][8];
#pragma unroll
  for (int c = 0; c < 8; ++c)
    Bf[0][c] = loadBfrag<F32>(wi, tbase * 16 + lr, c * 32 + quad * 8, 256);

#pragma unroll
  for (int nt = 0; nt < 6; ++nt) {
    const int cb = nt & 1;
    if (nt < 5) {
#pragma unroll
      for (int c = 0; c < 8; ++c)
        Bf[cb ^ 1][c] = loadBfrag<F32>(wi, (tbase + nt + 1) * 16 + lr, c * 32 + quad * 8, 256);
    }

    f32x4 a[4];
#pragma unroll
    for (int mt = 0; mt < 4; ++mt) a[mt] = (f32x4){0.f, 0.f, 0.f, 0.f};
#pragma unroll
    for (int c = 0; c < 8; ++c) {
#pragma unroll
      for (int mt = 0; mt < 4; ++mt)
        a[mt] = mfma16(Af[mt][c], Bf[cb][c], a[mt]);
    }

    const int nAbs  = (tbase + nt) * 16;
    const int type  = nAbs >> 8;
    const int dbase = nAbs & 255;
    if (type < 2) {
      const int d  = dbase + lr;
      const int h  = d >> 5, dd = d & 31;
      const int bh = bb_ * NH_ + h;
      u16* dst = (type == 0) ? qbuf : kbuf;
#pragma unroll
      for (int mt = 0; mt < 4; ++mt) {
        const int sL = mt * 16 + quad * 4;
#pragma unroll
        for (int i = 0; i < 4; ++i) {
          float v = a[mt][i];
          v = (type == 0) ? (v * v + 1e-6f) : (v + lmr[sL + i]);
          dst[((size_t)bh * S_ + sB + sL + i) * HD_ + dd] = f2b(v);
        }
      }
    } else {
      const int dv  = dbase + lr;
      const int hv  = dv >> 5, ddv = dv & 31;
      const int bhv = bb_ * NH_ + hv;
#pragma unroll
      for (int mt = 0; mt < 4; ++mt) {
        const int c16 = (sB >> 5) + (mt >> 1);
        const int slot16 = ((c16 * 2 + (ddv >> 4)) * 4 + quad) * 16 + (ddv & 15);
        uint2 pkv;
        pkv.x = pk2(a[mt][0], a[mt][1]);
        pkv.y = pk2(a[mt][2], a[mt][3]);
        *(uint2*)(vt + (size_t)bhv * (S_ * HD_) + slot16 * 8 + (mt & 1) * 4) = pkv;
      }
    }
  }
}

__global__ __launch_bounds__(256, 2) void ln_qkv_mfma(
    const void* __restrict__ xin, const void* __restrict__ rmask,
    const void* __restrict__ wi, const void* __restrict__ gamma,
    const void* __restrict__ beta,
    u16* __restrict__ qbuf, u16* __restrict__ kbuf, u16* __restrict__ vt)
{
  __shared__ __align__(16) u16 XnF[4 * 8 * 64 * 8];   // 32 KB
  __shared__ float lmr[64];
  if (sniff_mode(xin) == 0) ln_body<0>(xin, rmask, wi, gamma, beta, qbuf, kbuf, vt, XnF, lmr);
  else                      ln_body<1>(xin, rmask, wi, gamma, beta, qbuf, kbuf, vt, XnF, lmr);
}

// ============================================================
// Kernel 2: LDS-free flash attention, online softmax, 2 q-tiles/wave.
// Grid 1024 = (sq 0..3)*256 + bh (XCD swizzle). V sigma-key-permuted.
// (R10-proven structure, fast-cvt only change)
// ============================================================
__global__ __launch_bounds__(256, 3) void attn_mfma(
    const u16* __restrict__ qbuf, const u16* __restrict__ kbuf,
    const u16* __restrict__ vt, u16* __restrict__ ctx)
{
  __shared__ __align__(16) u16 OB[4][32 * 40];   // wave-private out transpose (10 KB)
  const int tid = threadIdx.x;
  const int bh = blockIdx.x & 255, sq = blockIdx.x >> 8;
  const int l = tid & 63, w = tid >> 6;
  const int lr = l & 15, quad = l >> 4;
  const size_t kvbase = (size_t)bh * (S_ * HD_);
  const int q0 = sq * 128 + w * 32;

  const float cE = 0.17677669529663688f * 1.4426950408889634f;

  const short8 qfA = *(const short8*)(qbuf + kvbase + (size_t)(q0 + lr) * HD_ + quad * 8);
  const short8 qfB = *(const short8*)(qbuf + kvbase + (size_t)(q0 + 16 + lr) * HD_ + quad * 8);
  const u16* kp = kbuf + kvbase + (size_t)lr * HD_ + quad * 8;
  const u16* vp = vt + kvbase;

  float mSA = -1e30f, lSA = 0.f, mSB = -1e30f, lSB = 0.f;
  f32x4 oA0 = {0.f,0.f,0.f,0.f}, oA1 = {0.f,0.f,0.f,0.f};
  f32x4 oB0 = {0.f,0.f,0.f,0.f}, oB1 = {0.f,0.f,0.f,0.f};

#pragma unroll
  for (int c = 0; c < 4; ++c) {
    f32x4 aA[8], aB[8];
#pragma unroll
    for (int j = 0; j < 8; ++j) {
      const short8 kf = *(const short8*)(kp + (c * 8 + j) * (16 * HD_));
      f32x4 z = {0.f,0.f,0.f,0.f};
      aA[j] = mfma16(kf, qfA, z);
      aB[j] = mfma16(kf, qfB, z);
    }

    float mcA = aA[0][0], mcB = aB[0][0];
#pragma unroll
    for (int j = 0; j < 8; ++j)
#pragma unroll
      for (int r = 0; r < 4; ++r) { mcA = fmaxf(mcA, aA[j][r]); mcB = fmaxf(mcB, aB[j][r]); }
    mcA = fmaxf(mcA, __shfl_xor(mcA, 16)); mcB = fmaxf(mcB, __shfl_xor(mcB, 16));
    mcA = fmaxf(mcA, __shfl_xor(mcA, 32)); mcB = fmaxf(mcB, __shfl_xor(mcB, 32));
    const float mNA = fmaxf(mSA, mcA * cE), mNB = fmaxf(mSB, mcB * cE);
    const float alA = exp2f(mSA - mNA),     alB = exp2f(mSB - mNB);
    float scA = 0.f, scB = 0.f;
#pragma unroll
    for (int j = 0; j < 8; ++j)
#pragma unroll
      for (int r = 0; r < 4; ++r) {
        const float pA = exp2f(fmaf(aA[j][r], cE, -mNA));
        const float pB = exp2f(fmaf(aB[j][r], cE, -mNB));
        aA[j][r] = pA; scA += pA;
        aB[j][r] = pB; scB += pB;
      }
    scA += __shfl_xor(scA, 16); scB += __shfl_xor(scB, 16);
    scA += __shfl_xor(scA, 32); scB += __shfl_xor(scB, 32);
    lSA = fmaf(lSA, alA, scA); mSA = mNA;
    lSB = fmaf(lSB, alB, scB); mSB = mNB;
#pragma unroll
    for (int r = 0; r < 4; ++r) {
      oA0[r] *= alA; oA1[r] *= alA;
      oB0[r] *= alB; oB1[r] *= alB;
    }

#pragma unroll
    for (int g = 0; g < 4; ++g) {
      const int c16 = c * 4 + g;
      const short8 v0 = *(const short8*)(vp + (((c16 * 8 +     quad) * 16 + lr) << 3));
      const short8 v1 = *(const short8*)(vp + (((c16 * 8 + 4 + quad) * 16 + lr) << 3));
      union { u32 u[4]; short8 s; } pa;
      pa.u[0] = pk2(aA[2*g][0],   aA[2*g][1]);
      pa.u[1] = pk2(aA[2*g][2],   aA[2*g][3]);
      pa.u[2] = pk2(aA[2*g+1][0], aA[2*g+1][1]);
      pa.u[3] = pk2(aA[2*g+1][2], aA[2*g+1][3]);
      oA0 = mfma16(pa.s, v0, oA0);
      oA1 = mfma16(pa.s, v1, oA1);
      pa.u[0] = pk2(aB[2*g][0],   aB[2*g][1]);
      pa.u[1] = pk2(aB[2*g][2],   aB[2*g][3]);
      pa.u[2] = pk2(aB[2*g+1][0], aB[2*g+1][1]);
      pa.u[3] = pk2(aB[2*g+1][2], aB[2*g+1][3]);
      oB0 = mfma16(pa.s, v0, oB0);
      oB1 = mfma16(pa.s, v1, oB1);
    }
  }
  const float invA = 1.f / lSA, invB = 1.f / lSB;

  u16* ob = OB[w];
#pragma unroll
  for (int r = 0; r < 4; ++r) {
    const int qq = quad * 4 + r;
    const float ivA = __shfl(invA, (l & 48) | qq);
    const float ivB = __shfl(invB, (l & 48) | qq);
    ob[qq * 40 + lr]             = f2b(oA0[r] * ivA);
    ob[qq * 40 + 16 + lr]        = f2b(oA1[r] * ivA);
    ob[(16 + qq) * 40 + lr]      = f2b(oB0[r] * ivB);
    ob[(16 + qq) * 40 + 16 + lr] = f2b(oB1[r] * ivB);
  }
#pragma unroll
  for (int t = 0; t < 2; ++t) {
    const int row = (l >> 2) + t * 16;
    const uint4 ov = *(const uint4*)(ob + row * 40 + (l & 3) * 8);
    *(uint4*)(ctx + kvbase + (size_t)(q0 + row) * HD_ + (l & 3) * 8) = ov;
  }
}

// ============================================================
// out-proj body (R10-proven structure).
// ============================================================
template<int F32>
__device__ __forceinline__ void proj_body(
    const u16* __restrict__ ctx, const void* __restrict__ xin,
    const void* __restrict__ wo, void* __restrict__ out,
    u16* XnF, u16* OutB)
{
  const int tid = threadIdx.x;
  const int l = tid & 63, w = tid >> 6;
  const int lr = l & 15, quad = l >> 4;
  const int row0 = blockIdx.x * 32;
  const int b = row0 >> 9, s0 = row0 & 511;

#pragma unroll
  for (int it = 0; it < 4; ++it) {
    const int idx = it * 256 + tid;
    const int dq = idx & 3, sl = (idx >> 2) & 31, h = idx >> 7;
    const uint4 cv = *(const uint4*)(ctx + ((size_t)(b * 8 + h) * S_ + s0 + sl) * HD_ + dq * 8);
    const int t = sl >> 4, rm = sl & 15;
    const int qds = dq ^ (rm & 3);
    *(uint4*)(XnF + (((t * 8 + h) * 64 + qds * 16 + rm) << 3)) = cv;
  }
  __syncthreads();

  const int lsw = (quad ^ (lr & 3)) * 16 + lr;
  short8 Af[2][8];
#pragma unroll
  for (int mt = 0; mt < 2; ++mt)
#pragma unroll
    for (int c = 0; c < 8; ++c)
      Af[mt][c] = *(const short8*)(XnF + (((mt * 8 + c) * 64 + lsw) << 3));

  short8 Bf[2][8];
#pragma unroll
  for (int c = 0; c < 8; ++c)
    Bf[0][c] = loadBfrag<F32>(wo, (w * 4) * 16 + lr, c * 32 + quad * 8, 256);

#pragma unroll
  for (int nt = 0; nt < 4; ++nt) {
    const int cb = nt & 1;
    if (nt < 3) {
#pragma unroll
      for (int c = 0; c < 8; ++c)
        Bf[cb ^ 1][c] = loadBfrag<F32>(wo, (w * 4 + nt + 1) * 16 + lr, c * 32 + quad * 8, 256);
    }
    const int n0 = (w * 4 + nt) * 16;
    f32x4 a0 = {0.f,0.f,0.f,0.f}, a1 = {0.f,0.f,0.f,0.f};
#pragma unroll
    for (int c = 0; c < 8; ++c) {
      a0 = mfma16(Af[0][c], Bf[cb][c], a0);
      a1 = mfma16(Af[1][c], Bf[cb][c], a1);
    }
#pragma unroll
    for (int m = 0; m < 2; ++m) {
      const f32x4 acc = m ? a1 : a0;
#pragma unroll
      for (int i = 0; i < 4; ++i)
        OutB[(m * 16 + quad * 4 + i) * 264 + n0 + lr] = f2b(acc[i]);
    }
  }
  __syncthreads();

  const int r  = tid >> 3;
  const int c8 = (tid & 7) * 4;
#pragma unroll
  for (int j8 = 0; j8 < 4; ++j8) {
    float xv[8]; load8<F32>(xin, (row0 + r) * 32 + c8 + j8, xv);
    float pv[8]; unp8(*(const uint4*)(OutB + r * 264 + (c8 + j8) * 8), pv);
    float ov[8];
#pragma unroll
    for (int j = 0; j < 8; ++j) ov[j] = (pv[j] + xv[j]) * 0.70710678f;
    store8<F32>(out, (row0 + r) * 32 + c8 + j8, ov);
  }
}

__global__ __launch_bounds__(256, 2) void proj_mfma(
    const u16* __restrict__ ctx, const void* __restrict__ xin,
    const void* __restrict__ wo, void* __restrict__ out)
{
  __shared__ __align__(16) u16 XnF[2 * 8 * 64 * 8];   // 16 KB
  __shared__ __align__(16) u16 OutB[32 * 264];        // 16.5 KB
  if (sniff_mode(xin) == 0) proj_body<0>(ctx, xin, wo, out, XnF, OutB);
  else                      proj_body<1>(ctx, xin, wo, out, XnF, OutB);
}

// ============================================================
extern "C" void kernel_launch(void* const* d_in, const int* in_sizes, int n_in,
                              void* d_out, int out_size, void* d_ws, size_t ws_size,
                              hipStream_t stream)
{
  const void* xin   = d_in[0];
  const void* rmask = d_in[1];
  const void* wi    = d_in[2];
  const void* wo    = d_in[3];
  const void* gam   = d_in[4];
  const void* bet   = d_in[5];

  u16* q   = (u16*)d_ws;                   // [256][512][32] bf16 (8 MB)
  u16* k   = q + 4194304;
  u16* vt  = k + 4194304;                  // sigma-permuted V (8 MB)
  u16* cxb = vt + 4194304;                 // ctx [bh][s][hd] bf16 (8 MB)

  ln_qkv_mfma<<<512,  256, 0, stream>>>(xin, rmask, wi, gam, bet, q, k, vt);
  attn_mfma  <<<1024, 256, 0, stream>>>(q, k, vt, cxb);
  proj_mfma  <<<512,  256, 0, stream>>>(cxb, xin, wo, d_out);
}